// Round 1
// baseline (1117.088 us; speedup 1.0000x reference)
//
#include <hip/hip_runtime.h>
#include <stdint.h>
#include <stddef.h>

// Problem constants
#define T_TOK 2048     // B*S tokens
#define DMODEL 1024
#define NHEAD 16
#define HDIM 64
#define NEXP 8
#define FDIM 4096
#define SLEN 1024
#define NBATCH 2
#define LN_EPS 1e-5f

typedef unsigned short u16;
typedef __attribute__((ext_vector_type(8))) short s16x8;   // 8 bf16 (4 VGPRs) MFMA frag
typedef __attribute__((ext_vector_type(4))) float f32x4;   // MFMA accumulator
typedef __attribute__((ext_vector_type(4))) unsigned short u16x4;
typedef __attribute__((ext_vector_type(8))) unsigned short u16x8;

__device__ __forceinline__ u16 f2bf(float x) {
  union { float f; unsigned int u; } v; v.f = x;
  unsigned int r = v.u + 0x7fffu + ((v.u >> 16) & 1u);  // RNE
  return (u16)(r >> 16);
}

// ---------------------------------------------------------------------------
// fp32 -> bf16 convert (vectorized, n divisible by 1024)
// ---------------------------------------------------------------------------
__global__ __launch_bounds__(256) void cvt_bf16(const float* __restrict__ x,
                                                u16* __restrict__ y, long n4) {
  long i = (long)blockIdx.x * 256 + threadIdx.x;
  if (i >= n4) return;
  float4 v = ((const float4*)x)[i];
  u16x4 o;
  o[0] = f2bf(v.x); o[1] = f2bf(v.y); o[2] = f2bf(v.z); o[3] = f2bf(v.w);
  ((u16x4*)y)[i] = o;
}

// ---------------------------------------------------------------------------
// Generic batched bf16 GEMM: C[z] = act(alpha * A[z] @ B[z]^T + bias[z])
// A: M x K (row-major, lda), B: N x K (row-major, ldb)  -> C: M x N (ldc)
// If cntp != nullptr: grouped-expert mode, M = cntp[z], rows offset by offp[z].
// ---------------------------------------------------------------------------
template<int BM, int BN, int OUTBF, int DOGELU, int HASBIAS>
__global__ __launch_bounds__(256) void gemm_bt(
    const u16* __restrict__ Ag, long lda, long sAz,
    const u16* __restrict__ Bg, long ldb, long sBz,
    void* __restrict__ Cg, long ldc, long sCz,
    const float* __restrict__ biasg, long sbz,
    int M, int N, int K, float alpha,
    const int* __restrict__ cntp, const int* __restrict__ offp) {
  constexpr int BK = 64;
  int z = blockIdx.z;
  const u16* A; const u16* Bp; char* C; const float* bias = nullptr;
  if (cntp) {
    M = cntp[z];
    long o = offp[z];
    A = Ag + o * lda;
    Bp = Bg + (long)z * sBz;
    C = (char*)Cg + o * ldc * (OUTBF ? 2 : 4);
    if (HASBIAS) bias = biasg + (long)z * sbz;
  } else {
    A = Ag + (long)z * sAz;
    Bp = Bg + (long)z * sBz;
    C = (char*)Cg + (long)z * sCz * (OUTBF ? 2 : 4);
    if (HASBIAS) bias = biasg;
  }
  int m0 = blockIdx.y * BM;
  if (m0 >= M) return;
  int n0 = blockIdx.x * BN;

  __shared__ u16 As[BM][BK];
  __shared__ u16 Bs[BN][BK];

  int tid = threadIdx.x;
  int lane = tid & 63, w = tid >> 6;
  constexpr int WM = BM / 2, WN = BN / 2, SM = WM / 16, SN = WN / 16;
  int wm = (w & 1) * WM, wn = (w >> 1) * WN;

  f32x4 acc[SM][SN];
  for (int i = 0; i < SM; i++)
    for (int j = 0; j < SN; j++)
      for (int r = 0; r < 4; r++) acc[i][j][r] = 0.f;

  int srow = tid >> 3;          // 0..31
  int scol = (tid & 7) * 8;     // 0..56

  for (int k0 = 0; k0 < K; k0 += BK) {
    __syncthreads();
    for (int p = 0; p < BM; p += 32) {
      int r = p + srow;
      int gr = m0 + r; if (gr > M - 1) gr = M - 1;   // M-tail clamp (expert mode)
      *(u16x8*)&As[r][scol] = *(const u16x8*)&A[(long)gr * lda + k0 + scol];
    }
    for (int p = 0; p < BN; p += 32) {
      int r = p + srow;
      *(u16x8*)&Bs[r][scol] = *(const u16x8*)&Bp[(long)(n0 + r) * ldb + k0 + scol];
    }
    __syncthreads();
    int q = lane >> 4, rr = lane & 15;
    for (int kk = 0; kk < 2; kk++) {
      s16x8 af[SM], bfv[SN];
      for (int i = 0; i < SM; i++) af[i] = *(const s16x8*)&As[wm + i * 16 + rr][kk * 32 + q * 8];
      for (int j = 0; j < SN; j++) bfv[j] = *(const s16x8*)&Bs[wn + j * 16 + rr][kk * 32 + q * 8];
      for (int i = 0; i < SM; i++)
        for (int j = 0; j < SN; j++)
          acc[i][j] = __builtin_amdgcn_mfma_f32_16x16x32_bf16(af[i], bfv[j], acc[i][j], 0, 0, 0);
    }
  }

  int q = lane >> 4, rr = lane & 15;
  for (int i = 0; i < SM; i++) {
    for (int j = 0; j < SN; j++) {
      int col = n0 + wn + j * 16 + rr;
      float bv = HASBIAS ? bias[col] : 0.f;
      for (int r = 0; r < 4; r++) {
        int row = m0 + wm + i * 16 + q * 4 + r;
        if (row < M) {
          float v = acc[i][j][r] * alpha + bv;
          if (DOGELU) v = 0.5f * v * (1.f + erff(v * 0.70710678118f));
          if (OUTBF) ((u16*)C)[(long)row * ldc + col] = f2bf(v);
          else ((float*)C)[(long)row * ldc + col] = v;
        }
      }
    }
  }
}

// ---------------------------------------------------------------------------
// Repack qkv (T x 3072 bf16) -> Q,K in (B,H,S,HD) bf16
// ---------------------------------------------------------------------------
__global__ __launch_bounds__(256) void repack_qk(const u16* __restrict__ qkv,
                                                 u16* __restrict__ Q, u16* __restrict__ Kb) {
  int t = blockIdx.x; int b = t >> 10; int s = t & 1023;
  int c = threadIdx.x * 4;
  int h = c >> 6, d = c & 63;
  long dst = ((long)(b * NHEAD + h) * SLEN + s) * HDIM + d;
  *(u16x4*)&Q[dst] = *(const u16x4*)&qkv[(long)t * 3072 + c];
  *(u16x4*)&Kb[dst] = *(const u16x4*)&qkv[(long)t * 3072 + 1024 + c];
}

// V part of qkv -> Vt (B,H,HD,S) bf16 (transposed via LDS tile)
__global__ __launch_bounds__(256) void transpose_v(const u16* __restrict__ qkv,
                                                   u16* __restrict__ vt) {
  __shared__ u16 tile[64][65];
  int s0 = blockIdx.x * 64, bh = blockIdx.y;
  int b = bh >> 4, h = bh & 15;
  int r = threadIdx.x >> 3, c = (threadIdx.x & 7) * 8;
  for (int p = 0; p < 64; p += 32) {
    u16x8 v = *(const u16x8*)&qkv[(long)(b * SLEN + s0 + p + r) * 3072 + 2048 + h * 64 + c];
    for (int j = 0; j < 8; j++) tile[p + r][c + j] = v[j];
  }
  __syncthreads();
  for (int p = 0; p < 64; p += 32) {
    int d = p + r;
    u16x8 v;
    for (int j = 0; j < 8; j++) v[j] = tile[c + j][d];
    *(u16x8*)&vt[((long)bh * 64 + d) * SLEN + s0 + c] = v;
  }
}

// (B,H,S,HD) bf16 -> (B,S,D) bf16
__global__ __launch_bounds__(256) void repack_o(const u16* __restrict__ o1,
                                                u16* __restrict__ o2) {
  int t = blockIdx.x; int b = t >> 10, s = t & 1023;
  int c = threadIdx.x * 4;
  int h = c >> 6, d = c & 63;
  *(u16x4*)&o2[(long)t * DMODEL + c] =
      *(const u16x4*)&o1[((long)(b * NHEAD + h) * SLEN + s) * HDIM + d];
}

// ---------------------------------------------------------------------------
// Row softmax: fp32 scores (z,S,S) -> bf16 probs
// ---------------------------------------------------------------------------
__global__ __launch_bounds__(256) void softmax_rows(const float* __restrict__ Sc,
                                                    u16* __restrict__ P) {
  int row = blockIdx.x, z = blockIdx.y;
  const float* src = Sc + ((long)z * SLEN + row) * SLEN;
  u16* dst = P + ((long)z * SLEN + row) * SLEN;
  int tid = threadIdx.x;
  float4 v = ((const float4*)src)[tid];
  float m = fmaxf(fmaxf(v.x, v.y), fmaxf(v.z, v.w));
  __shared__ float sm[4], ss[4];
  for (int o = 32; o; o >>= 1) m = fmaxf(m, __shfl_down(m, o));
  if ((tid & 63) == 0) sm[tid >> 6] = m;
  __syncthreads();
  m = fmaxf(fmaxf(sm[0], sm[1]), fmaxf(sm[2], sm[3]));
  float e0 = __expf(v.x - m), e1 = __expf(v.y - m), e2 = __expf(v.z - m), e3 = __expf(v.w - m);
  float s = e0 + e1 + e2 + e3;
  for (int o = 32; o; o >>= 1) s += __shfl_down(s, o);
  if ((tid & 63) == 0) ss[tid >> 6] = s;
  __syncthreads();
  s = ss[0] + ss[1] + ss[2] + ss[3];
  float inv = 1.f / s;
  u16x4 o4;
  o4[0] = f2bf(e0 * inv); o4[1] = f2bf(e1 * inv); o4[2] = f2bf(e2 * inv); o4[3] = f2bf(e3 * inv);
  ((u16x4*)dst)[tid] = o4;
}

// ---------------------------------------------------------------------------
// residual add + LayerNorm -> fp32 + bf16 copies
// ---------------------------------------------------------------------------
__global__ __launch_bounds__(256) void add_ln(const float* __restrict__ a,
                                              const float* __restrict__ b,
                                              const float* __restrict__ g,
                                              const float* __restrict__ bb,
                                              float* __restrict__ xf, u16* __restrict__ xb) {
  int t = blockIdx.x, tid = threadIdx.x;
  float4 va = ((const float4*)(a + (long)t * DMODEL))[tid];
  float4 vb = ((const float4*)(b + (long)t * DMODEL))[tid];
  float v0 = va.x + vb.x, v1 = va.y + vb.y, v2 = va.z + vb.z, v3 = va.w + vb.w;
  float s = v0 + v1 + v2 + v3;
  float s2 = v0 * v0 + v1 * v1 + v2 * v2 + v3 * v3;
  __shared__ float sa[4], sb[4];
  for (int o = 32; o; o >>= 1) { s += __shfl_down(s, o); s2 += __shfl_down(s2, o); }
  int lane = tid & 63, w = tid >> 6;
  if (lane == 0) { sa[w] = s; sb[w] = s2; }
  __syncthreads();
  s = sa[0] + sa[1] + sa[2] + sa[3];
  s2 = sb[0] + sb[1] + sb[2] + sb[3];
  float mu = s * (1.f / DMODEL);
  float var = s2 * (1.f / DMODEL) - mu * mu;
  float rs = rsqrtf(var + LN_EPS);
  float4 gg = ((const float4*)g)[tid];
  float4 bv = ((const float4*)bb)[tid];
  float4 o;
  o.x = (v0 - mu) * rs * gg.x + bv.x;
  o.y = (v1 - mu) * rs * gg.y + bv.y;
  o.z = (v2 - mu) * rs * gg.z + bv.z;
  o.w = (v3 - mu) * rs * gg.w + bv.w;
  ((float4*)(xf + (long)t * DMODEL))[tid] = o;
  u16x4 ob;
  ob[0] = f2bf(o.x); ob[1] = f2bf(o.y); ob[2] = f2bf(o.z); ob[3] = f2bf(o.w);
  ((u16x4*)(xb + (long)t * DMODEL))[tid] = ob;
}

// ---------------------------------------------------------------------------
// Gate: logits, full softmax (usage/aux), top-2 routing lists
// ---------------------------------------------------------------------------
__global__ __launch_bounds__(256) void gate_kernel(
    const float* __restrict__ xf, const float* __restrict__ gw, const float* __restrict__ gb,
    int* __restrict__ cnt, int* __restrict__ tok_list,
    int* __restrict__ tk_e, int* __restrict__ tk_pos, float* __restrict__ tk_prob,
    float* __restrict__ usage) {
  int wid = threadIdx.x >> 6, lane = threadIdx.x & 63;
  int t = blockIdx.x * 4 + wid;
  float xv[16];
  for (int j = 0; j < 16; j++) xv[j] = xf[(long)t * DMODEL + j * 64 + lane];
  float l[8];
  for (int e = 0; e < 8; e++) {
    float d = 0.f;
    for (int j = 0; j < 16; j++) d += xv[j] * gw[e * DMODEL + j * 64 + lane];
    for (int o = 32; o; o >>= 1) d += __shfl_down(d, o);
    l[e] = d;  // valid on lane 0 only
  }
  __shared__ float us[8];
  if (threadIdx.x < 8) us[threadIdx.x] = 0.f;
  __syncthreads();
  if (lane == 0) {
    float mx = -1e30f;
    for (int e = 0; e < 8; e++) { l[e] += gb[e]; mx = fmaxf(mx, l[e]); }
    float ex[8], sum = 0.f;
    for (int e = 0; e < 8; e++) { ex[e] = expf(l[e] - mx); sum += ex[e]; }
    float inv = 1.f / sum;
    for (int e = 0; e < 8; e++) atomicAdd(&us[e], ex[e] * inv);
    int i1 = 0;
    for (int e = 1; e < 8; e++) if (l[e] > l[i1]) i1 = e;
    int i2 = (i1 == 0) ? 1 : 0;
    for (int e = 0; e < 8; e++) if (e != i1 && l[e] > l[i2]) i2 = e;
    float bb = expf(l[i2] - l[i1]);
    float p1 = 1.f / (1.f + bb), p2 = bb / (1.f + bb);
    int pos1 = atomicAdd(&cnt[i1], 1);
    tok_list[i1 * 2048 + pos1] = t;
    tk_e[2 * t] = i1; tk_pos[2 * t] = pos1; tk_prob[2 * t] = p1;
    int pos2 = atomicAdd(&cnt[i2], 1);
    tok_list[i2 * 2048 + pos2] = t;
    tk_e[2 * t + 1] = i2; tk_pos[2 * t + 1] = pos2; tk_prob[2 * t + 1] = p2;
  }
  __syncthreads();
  if (threadIdx.x < 8) atomicAdd(&usage[threadIdx.x], us[threadIdx.x]);
}

__global__ void finalize_gate(const int* __restrict__ cnt, int* __restrict__ offp,
                              const float* __restrict__ usage, float* __restrict__ aux_out) {
  if (threadIdx.x == 0) {
    int o = 0;
    for (int e = 0; e < 8; e++) { offp[e] = o; o += cnt[e]; }
    float s = 0.f;
    for (int e = 0; e < 8; e++) { float u = usage[e] * (1.f / T_TOK); s += u * u; }
    aux_out[0] = (float)NEXP * s;
  }
}

// gather x rows per expert into compact buffer
__global__ __launch_bounds__(256) void gather_x(const u16* __restrict__ xb,
                                                const int* __restrict__ cnt,
                                                const int* __restrict__ offp,
                                                const int* __restrict__ tok_list,
                                                u16* __restrict__ xg) {
  int e = blockIdx.y, i = blockIdx.x;
  if (i >= cnt[e]) return;
  int t = tok_list[e * 2048 + i];
  long j = offp[e] + i;
  ((uint2*)(xg + j * DMODEL))[threadIdx.x] =
      ((const uint2*)(xb + (long)t * DMODEL))[threadIdx.x];
}

// weighted expert-output combine + residual + LN2 -> final output
__global__ __launch_bounds__(256) void moe_ln2(
    const float* __restrict__ xf, const float* __restrict__ y,
    const int* __restrict__ offp, const int* __restrict__ tk_e,
    const int* __restrict__ tk_pos, const float* __restrict__ tk_prob,
    const float* __restrict__ g, const float* __restrict__ bb, float* __restrict__ out) {
  int t = blockIdx.x, tid = threadIdx.x;
  int e0 = tk_e[2 * t], e1 = tk_e[2 * t + 1];
  long j0 = (long)offp[e0] + tk_pos[2 * t];
  long j1 = (long)offp[e1] + tk_pos[2 * t + 1];
  float p0 = tk_prob[2 * t], p1 = tk_prob[2 * t + 1];
  float4 vx = ((const float4*)(xf + (long)t * DMODEL))[tid];
  float4 y0 = ((const float4*)(y + j0 * DMODEL))[tid];
  float4 y1 = ((const float4*)(y + j1 * DMODEL))[tid];
  float v0 = vx.x + p0 * y0.x + p1 * y1.x;
  float v1 = vx.y + p0 * y0.y + p1 * y1.y;
  float v2 = vx.z + p0 * y0.z + p1 * y1.z;
  float v3 = vx.w + p0 * y0.w + p1 * y1.w;
  float s = v0 + v1 + v2 + v3;
  float s2 = v0 * v0 + v1 * v1 + v2 * v2 + v3 * v3;
  __shared__ float sa[4], sb[4];
  for (int o = 32; o; o >>= 1) { s += __shfl_down(s, o); s2 += __shfl_down(s2, o); }
  int lane = tid & 63, w = tid >> 6;
  if (lane == 0) { sa[w] = s; sb[w] = s2; }
  __syncthreads();
  s = sa[0] + sa[1] + sa[2] + sa[3];
  s2 = sb[0] + sb[1] + sb[2] + sb[3];
  float mu = s * (1.f / DMODEL);
  float var = s2 * (1.f / DMODEL) - mu * mu;
  float rs = rsqrtf(var + LN_EPS);
  float4 gg = ((const float4*)g)[tid];
  float4 bv = ((const float4*)bb)[tid];
  float4 o;
  o.x = (v0 - mu) * rs * gg.x + bv.x;
  o.y = (v1 - mu) * rs * gg.y + bv.y;
  o.z = (v2 - mu) * rs * gg.z + bv.z;
  o.w = (v3 - mu) * rs * gg.w + bv.w;
  ((float4*)(out + (long)t * DMODEL))[tid] = o;
}

// ---------------------------------------------------------------------------
extern "C" void kernel_launch(void* const* d_in, const int* in_sizes, int n_in,
                              void* d_out, int out_size, void* d_ws, size_t ws_size,
                              hipStream_t stream) {
  const float* src  = (const float*)d_in[0];
  const float* inw  = (const float*)d_in[1];
  const float* inb  = (const float*)d_in[2];
  const float* outw = (const float*)d_in[3];
  const float* outb = (const float*)d_in[4];
  const float* gw   = (const float*)d_in[5];
  const float* gb   = (const float*)d_in[6];
  const float* w1   = (const float*)d_in[7];
  const float* b1   = (const float*)d_in[8];
  const float* w2   = (const float*)d_in[9];
  const float* b2   = (const float*)d_in[10];
  const float* g1   = (const float*)d_in[11];
  const float* bb1  = (const float*)d_in[12];
  const float* g2   = (const float*)d_in[13];
  const float* bb2  = (const float*)d_in[14];
  float* out = (float*)d_out;

  char* w = (char*)d_ws;
  auto alloc = [&](size_t bytes) {
    char* p = w;
    w += (bytes + 255) & ~(size_t)255;
    return p;
  };

  // control block first (single memset covers cnt+off+usage)
  int*   cnt     = (int*)alloc(8 * 4);
  int*   offp    = (int*)alloc(8 * 4);
  float* usage   = (float*)alloc(8 * 4);
  int*   tok_list= (int*)alloc((size_t)NEXP * 2048 * 4);
  int*   tk_e    = (int*)alloc((size_t)2 * T_TOK * 4);
  int*   tk_pos  = (int*)alloc((size_t)2 * T_TOK * 4);
  float* tk_prob = (float*)alloc((size_t)2 * T_TOK * 4);

  u16* src_bf  = (u16*)alloc((size_t)T_TOK * DMODEL * 2);
  u16* inw_bf  = (u16*)alloc((size_t)3 * DMODEL * DMODEL * 2);
  u16* outw_bf = (u16*)alloc((size_t)DMODEL * DMODEL * 2);
  u16* w1_bf   = (u16*)alloc((size_t)NEXP * FDIM * DMODEL * 2);
  u16* w2_bf   = (u16*)alloc((size_t)NEXP * DMODEL * FDIM * 2);
  u16* qkv_bf  = (u16*)alloc((size_t)T_TOK * 3 * DMODEL * 2);
  u16* q_bf    = (u16*)alloc((size_t)T_TOK * DMODEL * 2);
  u16* k_bf    = (u16*)alloc((size_t)T_TOK * DMODEL * 2);
  u16* vt_bf   = (u16*)alloc((size_t)T_TOK * DMODEL * 2);
  float* scores= (float*)alloc((size_t)8 * SLEN * SLEN * 4);  // 8-slice chunk
  u16* probs   = (u16*)alloc((size_t)8 * SLEN * SLEN * 2);
  u16* o1_bf   = (u16*)alloc((size_t)T_TOK * DMODEL * 2);     // (B,H,S,HD)
  u16* o2_bf   = (u16*)alloc((size_t)T_TOK * DMODEL * 2);     // (B,S,D)
  float* attn_f= (float*)alloc((size_t)T_TOK * DMODEL * 4);
  float* x_f   = (float*)alloc((size_t)T_TOK * DMODEL * 4);
  u16* x_bf    = (u16*)alloc((size_t)T_TOK * DMODEL * 2);
  u16* xg_bf   = (u16*)alloc((size_t)2 * T_TOK * DMODEL * 2); // 4096 compact rows
  u16* h_bf    = (u16*)alloc((size_t)2 * T_TOK * FDIM * 2);
  float* y_f   = (float*)alloc((size_t)2 * T_TOK * DMODEL * 4);
  (void)ws_size; (void)n_in; (void)in_sizes; (void)out_size;

  hipMemsetAsync(cnt, 0, 3 * 256, stream);  // cnt, offp, usage regions

  // bf16 conversions
  cvt_bf16<<<(T_TOK * DMODEL / 4 + 255) / 256, 256, 0, stream>>>(src, src_bf, T_TOK * DMODEL / 4);
  cvt_bf16<<<(3 * DMODEL * DMODEL / 4 + 255) / 256, 256, 0, stream>>>(inw, inw_bf, 3L * DMODEL * DMODEL / 4);
  cvt_bf16<<<(DMODEL * DMODEL / 4 + 255) / 256, 256, 0, stream>>>(outw, outw_bf, (long)DMODEL * DMODEL / 4);
  cvt_bf16<<<(int)((long)NEXP * FDIM * DMODEL / 4 / 256), 256, 0, stream>>>(w1, w1_bf, (long)NEXP * FDIM * DMODEL / 4);
  cvt_bf16<<<(int)((long)NEXP * DMODEL * FDIM / 4 / 256), 256, 0, stream>>>(w2, w2_bf, (long)NEXP * DMODEL * FDIM / 4);

  // QKV projection: (2048x1024) @ (3072x1024)^T + b -> bf16
  gemm_bt<128, 128, 1, 0, 1><<<dim3(24, 16, 1), 256, 0, stream>>>(
      src_bf, DMODEL, 0, inw_bf, DMODEL, 0, qkv_bf, 3 * DMODEL, 0,
      inb, 0, T_TOK, 3 * DMODEL, DMODEL, 1.f, nullptr, nullptr);

  repack_qk<<<T_TOK, 256, 0, stream>>>(qkv_bf, q_bf, k_bf);
  transpose_v<<<dim3(16, 32), 256, 0, stream>>>(qkv_bf, vt_bf);

  // Attention in 4 chunks of 8 (b,h) slices
  for (int c = 0; c < 4; c++) {
    long boff = (long)c * 8 * SLEN * HDIM;
    gemm_bt<128, 128, 0, 0, 0><<<dim3(8, 8, 8), 256, 0, stream>>>(
        q_bf + boff, HDIM, (long)SLEN * HDIM,
        k_bf + boff, HDIM, (long)SLEN * HDIM,
        scores, SLEN, (long)SLEN * SLEN,
        nullptr, 0, SLEN, SLEN, HDIM, 0.125f, nullptr, nullptr);
    softmax_rows<<<dim3(SLEN, 8), 256, 0, stream>>>(scores, probs);
    gemm_bt<128, 64, 1, 0, 0><<<dim3(1, 8, 8), 256, 0, stream>>>(
        probs, SLEN, (long)SLEN * SLEN,
        vt_bf + (long)c * 8 * HDIM * SLEN, SLEN, (long)HDIM * SLEN,
        o1_bf + boff, HDIM, (long)SLEN * HDIM,
        nullptr, 0, SLEN, HDIM, SLEN, 1.f, nullptr, nullptr);
  }

  repack_o<<<T_TOK, 256, 0, stream>>>(o1_bf, o2_bf);

  // output projection -> fp32
  gemm_bt<128, 128, 0, 0, 1><<<dim3(8, 16, 1), 256, 0, stream>>>(
      o2_bf, DMODEL, 0, outw_bf, DMODEL, 0, attn_f, DMODEL, 0,
      outb, 0, T_TOK, DMODEL, DMODEL, 1.f, nullptr, nullptr);

  // residual + LN1
  add_ln<<<T_TOK, 256, 0, stream>>>(src, attn_f, g1, bb1, x_f, x_bf);

  // gate + routing
  gate_kernel<<<T_TOK / 4, 256, 0, stream>>>(x_f, gw, gb, cnt, tok_list,
                                             tk_e, tk_pos, tk_prob, usage);
  finalize_gate<<<1, 64, 0, stream>>>(cnt, offp, usage, out + (long)T_TOK * DMODEL);

  gather_x<<<dim3(2048, 8), 256, 0, stream>>>(x_bf, cnt, offp, tok_list, xg_bf);

  // FFN1 (grouped by expert, gelu fused) -> bf16
  gemm_bt<128, 128, 1, 1, 1><<<dim3(32, 16, 8), 256, 0, stream>>>(
      xg_bf, DMODEL, 0, w1_bf, DMODEL, (long)FDIM * DMODEL, h_bf, FDIM, 0,
      b1, FDIM, 0, FDIM, DMODEL, 1.f, cnt, offp);

  // FFN2 (grouped) -> fp32
  gemm_bt<128, 128, 0, 0, 1><<<dim3(8, 16, 8), 256, 0, stream>>>(
      h_bf, FDIM, 0, w2_bf, FDIM, (long)DMODEL * FDIM, y_f, DMODEL, 0,
      b2, DMODEL, 0, DMODEL, FDIM, 1.f, cnt, offp);

  // combine + residual + LN2 -> output
  moe_ln2<<<T_TOK, 256, 0, stream>>>(x_f, y_f, offp, tk_e, tk_pos, tk_prob,
                                     g2, bb2, out);
}

// Round 2
// 966.676 us; speedup vs baseline: 1.1556x; 1.1556x over previous
//
#include <hip/hip_runtime.h>
#include <stdint.h>
#include <stddef.h>

// Problem constants
#define T_TOK 2048     // B*S tokens
#define DMODEL 1024
#define NHEAD 16
#define HDIM 64
#define NEXP 8
#define FDIM 4096
#define SLEN 1024
#define NBATCH 2
#define LN_EPS 1e-5f

typedef unsigned short u16;
typedef __attribute__((ext_vector_type(8))) short s16x8;   // 8 bf16 (4 VGPRs) MFMA frag
typedef __attribute__((ext_vector_type(4))) float f32x4;   // MFMA accumulator
typedef __attribute__((ext_vector_type(4))) unsigned short u16x4;
typedef __attribute__((ext_vector_type(8))) unsigned short u16x8;

typedef __attribute__((address_space(1))) void gvoid;      // global
typedef __attribute__((address_space(3))) void lvoid;      // LDS

__device__ __forceinline__ u16 f2bf(float x) {
  union { float f; unsigned int u; } v; v.f = x;
  unsigned int r = v.u + 0x7fffu + ((v.u >> 16) & 1u);  // RNE
  return (u16)(r >> 16);
}

// async global->LDS, 16B per lane. dest semantics: wave-uniform base + lane*16.
__device__ __forceinline__ void gl_lds16(const u16* g, u16* l) {
  __builtin_amdgcn_global_load_lds((gvoid*)g, (lvoid*)l, 16, 0, 0);
}

// ---------------------------------------------------------------------------
// fp32 -> bf16 convert
// ---------------------------------------------------------------------------
__global__ __launch_bounds__(256) void cvt_bf16(const float* __restrict__ x,
                                                u16* __restrict__ y, long n4) {
  long i = (long)blockIdx.x * 256 + threadIdx.x;
  if (i >= n4) return;
  float4 v = ((const float4*)x)[i];
  u16x4 o;
  o[0] = f2bf(v.x); o[1] = f2bf(v.y); o[2] = f2bf(v.z); o[3] = f2bf(v.w);
  ((u16x4*)y)[i] = o;
}

// ---------------------------------------------------------------------------
// 128x128 bf16 GEMM: C[z] = act(A[z] @ B[z]^T + bias[z])
// A: M x K (row-major, lda), B: N x K (row-major, ldb)  -> C: M x N (ldc)
// If cntp: grouped-expert mode, M = cntp[z], rows offset by offp[z].
// LDS: XOR-swizzled granules (slot = g ^ (row&7)), staged via global_load_lds.
// ---------------------------------------------------------------------------
template<int OUTBF, int DOGELU, int HASBIAS>
__global__ __launch_bounds__(256) void gemm_bt(
    const u16* __restrict__ Ag, long lda,
    const u16* __restrict__ Bg, long ldb, long sBz,
    void* __restrict__ Cg, long ldc,
    const float* __restrict__ biasg, long sbz,
    int M, int N, int K,
    const int* __restrict__ cntp, const int* __restrict__ offp) {
  int z = blockIdx.z;
  const u16* A; const u16* Bp; char* C; const float* bias = nullptr;
  int Mloc = M;
  if (cntp) {
    Mloc = cntp[z];
    long o = offp[z];
    A = Ag + o * lda;
    Bp = Bg + (long)z * sBz;
    C = (char*)Cg + o * ldc * (OUTBF ? 2 : 4);
    if (HASBIAS) bias = biasg + (long)z * sbz;
  } else {
    A = Ag; Bp = Bg; C = (char*)Cg;
    if (HASBIAS) bias = biasg;
  }
  int m0 = blockIdx.y * 128;
  if (m0 >= Mloc) return;
  int n0 = blockIdx.x * 128;

  __shared__ u16 As[128][64];
  __shared__ u16 Bs[128][64];

  int tid = threadIdx.x;
  int lane = tid & 63, w = tid >> 6;
  int lrow = lane >> 3;                       // 0..7
  int sg8 = ((lane & 7) ^ lrow) * 8;          // swizzled source granule (elems)
  int q = lane >> 4, rr = lane & 15;
  int wm = (w & 1) * 64, wn = (w >> 1) * 64;

  f32x4 acc[4][4];
  for (int i = 0; i < 4; i++)
    for (int j = 0; j < 4; j++)
      for (int r = 0; r < 4; r++) acc[i][j][r] = 0.f;

  for (int k0 = 0; k0 < K; k0 += 64) {
    __syncthreads();
    for (int p = 0; p < 4; p++) {
      int rb = p * 32 + w * 8;                // wave's LDS row base
      int gr = m0 + rb + lrow; if (gr > Mloc - 1) gr = Mloc - 1;  // M-tail clamp
      gl_lds16(A + (long)gr * lda + k0 + sg8, &As[rb][0] + lane * 8);
      gl_lds16(Bp + (long)(n0 + rb + lrow) * ldb + k0 + sg8, &Bs[rb][0] + lane * 8);
    }
    __syncthreads();
    for (int kk = 0; kk < 2; kk++) {
      int slot = (((kk * 4 + q) ^ (rr & 7)) * 8);
      s16x8 af[4], bfv[4];
      for (int i = 0; i < 4; i++) af[i] = *(const s16x8*)&As[wm + i * 16 + rr][slot];
      for (int j = 0; j < 4; j++) bfv[j] = *(const s16x8*)&Bs[wn + j * 16 + rr][slot];
      for (int i = 0; i < 4; i++)
        for (int j = 0; j < 4; j++)
          acc[i][j] = __builtin_amdgcn_mfma_f32_16x16x32_bf16(af[i], bfv[j], acc[i][j], 0, 0, 0);
    }
  }

  for (int i = 0; i < 4; i++) {
    for (int j = 0; j < 4; j++) {
      int col = n0 + wn + j * 16 + rr;
      float bv = HASBIAS ? bias[col] : 0.f;
      for (int r = 0; r < 4; r++) {
        int row = m0 + wm + i * 16 + q * 4 + r;
        if (row < Mloc) {
          float v = acc[i][j][r] + bv;
          if (DOGELU) v = 0.5f * v * (1.f + erff(v * 0.70710678118f));
          if (OUTBF) ((u16*)C)[(long)row * ldc + col] = f2bf(v);
          else ((float*)C)[(long)row * ldc + col] = v;
        }
      }
    }
  }
}

// ---------------------------------------------------------------------------
// V part of qkv -> Vt (B,H,HD,S) bf16 (transposed via LDS tile)
// ---------------------------------------------------------------------------
__global__ __launch_bounds__(256) void transpose_v(const u16* __restrict__ qkv,
                                                   u16* __restrict__ vt) {
  __shared__ u16 tile[64][65];
  int s0 = blockIdx.x * 64, bh = blockIdx.y;
  int b = bh >> 4, h = bh & 15;
  int r = threadIdx.x >> 3, c = (threadIdx.x & 7) * 8;
  for (int p = 0; p < 64; p += 32) {
    u16x8 v = *(const u16x8*)&qkv[(long)(b * SLEN + s0 + p + r) * 3072 + 2048 + h * 64 + c];
    for (int j = 0; j < 8; j++) tile[p + r][c + j] = v[j];
  }
  __syncthreads();
  for (int p = 0; p < 64; p += 32) {
    int d = p + r;
    u16x8 v;
    for (int j = 0; j < 8; j++) v[j] = tile[c + j][d];
    *(u16x8*)&vt[((long)bh * 64 + d) * SLEN + s0 + c] = v;
  }
}

// ---------------------------------------------------------------------------
// Fused flash attention: per (q-tile 128, b*h) block. Writes (B,S,D) bf16.
// qkv: (B,S,3D) bf16; vt: (B,H,HD,S) bf16.
// ---------------------------------------------------------------------------
__global__ __launch_bounds__(256) void fused_attn(const u16* __restrict__ qkv,
                                                  const u16* __restrict__ vt,
                                                  u16* __restrict__ o2) {
  __shared__ u16 Qs[128][64];   // swizzled
  __shared__ u16 Ks[64][64];    // swizzled
  __shared__ u16 Vs[64][64];    // swizzled (rows = head-dim d, cols = 64 keys)
  __shared__ u16 Ps[128][72];   // padded (stride 144B = 9x16, bank-rotate 4)

  int qt = blockIdx.x, bh = blockIdx.y;
  int b = bh >> 4, h = bh & 15;
  const u16* base = qkv + (long)b * SLEN * 3072 + h * 64;
  const u16* vbase = vt + (long)bh * HDIM * SLEN;

  int tid = threadIdx.x, lane = tid & 63, w = tid >> 6;
  int lrow = lane >> 3;
  int sg8 = ((lane & 7) ^ lrow) * 8;
  int q = lane >> 4, rr = lane & 15;
  int wm = w * 32;

  // stage Q once (rows qt*128 + r)
  for (int p = 0; p < 4; p++) {
    int rb = p * 32 + w * 8;
    gl_lds16(base + (long)(qt * 128 + rb + lrow) * 3072 + sg8, &Qs[rb][0] + lane * 8);
  }

  f32x4 O[2][4];
  float mi[2][4], li[2][4];
  for (int i = 0; i < 2; i++)
    for (int r = 0; r < 4; r++) { mi[i][r] = -1e30f; li[i][r] = 0.f; }
  for (int i = 0; i < 2; i++)
    for (int jn = 0; jn < 4; jn++)
      for (int r = 0; r < 4; r++) O[i][jn][r] = 0.f;

  for (int kt = 0; kt < 16; kt++) {
    __syncthreads();   // prev-iter readers done (also drains Q loads on iter 0)
    for (int p = 0; p < 2; p++) {
      int rb = p * 32 + w * 8;
      // K tile: rows = keys kt*64.., cols = head dims
      gl_lds16(base + (long)(kt * 64 + rb + lrow) * 3072 + 1024 + sg8, &Ks[rb][0] + lane * 8);
      // V tile (pre-transposed): rows = head dim d, cols = keys kt*64..
      gl_lds16(vbase + (long)(rb + lrow) * SLEN + kt * 64 + sg8, &Vs[rb][0] + lane * 8);
    }
    __syncthreads();

    // S = Q @ K^T  (M=128 x N=64, K=64)
    f32x4 S[2][4];
    for (int i = 0; i < 2; i++)
      for (int j = 0; j < 4; j++)
        for (int r = 0; r < 4; r++) S[i][j][r] = 0.f;
    for (int ks = 0; ks < 2; ks++) {
      int slot = (((ks * 4 + q) ^ (rr & 7)) * 8);
      s16x8 aq0 = *(const s16x8*)&Qs[wm + rr][slot];
      s16x8 aq1 = *(const s16x8*)&Qs[wm + 16 + rr][slot];
      for (int j = 0; j < 4; j++) {
        s16x8 bk = *(const s16x8*)&Ks[j * 16 + rr][slot];
        S[0][j] = __builtin_amdgcn_mfma_f32_16x16x32_bf16(aq0, bk, S[0][j], 0, 0, 0);
        S[1][j] = __builtin_amdgcn_mfma_f32_16x16x32_bf16(aq1, bk, S[1][j], 0, 0, 0);
      }
    }

    // online softmax (rows = wm + i*16 + q*4 + r, shared by the 16 lanes of this q-group)
    for (int i = 0; i < 2; i++) {
      for (int r = 0; r < 4; r++) {
        float mx = -1e30f;
        for (int j = 0; j < 4; j++) mx = fmaxf(mx, S[i][j][r]);
        for (int o = 1; o < 16; o <<= 1) mx = fmaxf(mx, __shfl_xor(mx, o));
        mx *= 0.125f;
        float mnew = fmaxf(mi[i][r], mx);
        float al = __expf(mi[i][r] - mnew);
        mi[i][r] = mnew;
        float ps = 0.f;
        for (int j = 0; j < 4; j++) {
          float e = __expf(S[i][j][r] * 0.125f - mnew);
          S[i][j][r] = e;
          ps += e;
        }
        for (int o = 1; o < 16; o <<= 1) ps += __shfl_xor(ps, o);
        li[i][r] = li[i][r] * al + ps;
        for (int jn = 0; jn < 4; jn++) O[i][jn][r] *= al;
      }
    }

    // P -> LDS (C-layout scatter; wave-private rows, but barrier for safety)
    for (int i = 0; i < 2; i++)
      for (int j = 0; j < 4; j++)
        for (int r = 0; r < 4; r++)
          Ps[wm + i * 16 + q * 4 + r][j * 16 + rr] = f2bf(S[i][j][r]);
    __syncthreads();

    // O += P @ V   (A = P[qrow][key], B^T[n=d][k=key] = Vs)
    for (int ks = 0; ks < 2; ks++) {
      s16x8 ap0 = *(const s16x8*)&Ps[wm + rr][ks * 32 + q * 8];
      s16x8 ap1 = *(const s16x8*)&Ps[wm + 16 + rr][ks * 32 + q * 8];
      int slot = (((ks * 4 + q) ^ (rr & 7)) * 8);
      for (int jn = 0; jn < 4; jn++) {
        s16x8 bv = *(const s16x8*)&Vs[jn * 16 + rr][slot];
        O[0][jn] = __builtin_amdgcn_mfma_f32_16x16x32_bf16(ap0, bv, O[0][jn], 0, 0, 0);
        O[1][jn] = __builtin_amdgcn_mfma_f32_16x16x32_bf16(ap1, bv, O[1][jn], 0, 0, 0);
      }
    }
  }

  // epilogue: out row s = qt*128 + wm + i*16 + q*4 + r, col h*64 + jn*16 + rr
  for (int i = 0; i < 2; i++)
    for (int r = 0; r < 4; r++) {
      float inv = 1.f / li[i][r];
      int s = qt * 128 + wm + i * 16 + q * 4 + r;
      long rowp = ((long)(b * SLEN + s)) * DMODEL + h * 64;
      for (int jn = 0; jn < 4; jn++)
        o2[rowp + jn * 16 + rr] = f2bf(O[i][jn][r] * inv);
    }
}

// ---------------------------------------------------------------------------
// residual add + LayerNorm -> fp32 + bf16 copies
// ---------------------------------------------------------------------------
__global__ __launch_bounds__(256) void add_ln(const float* __restrict__ a,
                                              const float* __restrict__ b,
                                              const float* __restrict__ g,
                                              const float* __restrict__ bb,
                                              float* __restrict__ xf, u16* __restrict__ xb) {
  int t = blockIdx.x, tid = threadIdx.x;
  float4 va = ((const float4*)(a + (long)t * DMODEL))[tid];
  float4 vb = ((const float4*)(b + (long)t * DMODEL))[tid];
  float v0 = va.x + vb.x, v1 = va.y + vb.y, v2 = va.z + vb.z, v3 = va.w + vb.w;
  float s = v0 + v1 + v2 + v3;
  float s2 = v0 * v0 + v1 * v1 + v2 * v2 + v3 * v3;
  __shared__ float sa[4], sb[4];
  for (int o = 32; o; o >>= 1) { s += __shfl_down(s, o); s2 += __shfl_down(s2, o); }
  int lane = tid & 63, w = tid >> 6;
  if (lane == 0) { sa[w] = s; sb[w] = s2; }
  __syncthreads();
  s = sa[0] + sa[1] + sa[2] + sa[3];
  s2 = sb[0] + sb[1] + sb[2] + sb[3];
  float mu = s * (1.f / DMODEL);
  float var = s2 * (1.f / DMODEL) - mu * mu;
  float rs = rsqrtf(var + LN_EPS);
  float4 gg = ((const float4*)g)[tid];
  float4 bv = ((const float4*)bb)[tid];
  float4 o;
  o.x = (v0 - mu) * rs * gg.x + bv.x;
  o.y = (v1 - mu) * rs * gg.y + bv.y;
  o.z = (v2 - mu) * rs * gg.z + bv.z;
  o.w = (v3 - mu) * rs * gg.w + bv.w;
  ((float4*)(xf + (long)t * DMODEL))[tid] = o;
  u16x4 ob;
  ob[0] = f2bf(o.x); ob[1] = f2bf(o.y); ob[2] = f2bf(o.z); ob[3] = f2bf(o.w);
  ((u16x4*)(xb + (long)t * DMODEL))[tid] = ob;
}

// ---------------------------------------------------------------------------
// Gate: logits, full softmax (usage/aux), top-2 routing lists
// ---------------------------------------------------------------------------
__global__ __launch_bounds__(256) void gate_kernel(
    const float* __restrict__ xf, const float* __restrict__ gw, const float* __restrict__ gb,
    int* __restrict__ cnt, int* __restrict__ tok_list,
    int* __restrict__ tk_e, int* __restrict__ tk_pos, float* __restrict__ tk_prob,
    float* __restrict__ usage) {
  int wid = threadIdx.x >> 6, lane = threadIdx.x & 63;
  int t = blockIdx.x * 4 + wid;
  float xv[16];
  for (int j = 0; j < 16; j++) xv[j] = xf[(long)t * DMODEL + j * 64 + lane];
  float l[8];
  for (int e = 0; e < 8; e++) {
    float d = 0.f;
    for (int j = 0; j < 16; j++) d += xv[j] * gw[e * DMODEL + j * 64 + lane];
    for (int o = 32; o; o >>= 1) d += __shfl_down(d, o);
    l[e] = d;  // valid on lane 0 only
  }
  __shared__ float us[8];
  if (threadIdx.x < 8) us[threadIdx.x] = 0.f;
  __syncthreads();
  if (lane == 0) {
    float mx = -1e30f;
    for (int e = 0; e < 8; e++) { l[e] += gb[e]; mx = fmaxf(mx, l[e]); }
    float ex[8], sum = 0.f;
    for (int e = 0; e < 8; e++) { ex[e] = expf(l[e] - mx); sum += ex[e]; }
    float inv = 1.f / sum;
    for (int e = 0; e < 8; e++) atomicAdd(&us[e], ex[e] * inv);
    int i1 = 0;
    for (int e = 1; e < 8; e++) if (l[e] > l[i1]) i1 = e;
    int i2 = (i1 == 0) ? 1 : 0;
    for (int e = 0; e < 8; e++) if (e != i1 && l[e] > l[i2]) i2 = e;
    float bb = expf(l[i2] - l[i1]);
    float p1 = 1.f / (1.f + bb), p2 = bb / (1.f + bb);
    int pos1 = atomicAdd(&cnt[i1], 1);
    tok_list[i1 * 2048 + pos1] = t;
    tk_e[2 * t] = i1; tk_pos[2 * t] = pos1; tk_prob[2 * t] = p1;
    int pos2 = atomicAdd(&cnt[i2], 1);
    tok_list[i2 * 2048 + pos2] = t;
    tk_e[2 * t + 1] = i2; tk_pos[2 * t + 1] = pos2; tk_prob[2 * t + 1] = p2;
  }
  __syncthreads();
  if (threadIdx.x < 8) atomicAdd(&usage[threadIdx.x], us[threadIdx.x]);
}

__global__ void finalize_gate(const int* __restrict__ cnt, int* __restrict__ offp,
                              const float* __restrict__ usage, float* __restrict__ aux_out) {
  if (threadIdx.x == 0) {
    int o = 0;
    for (int e = 0; e < 8; e++) { offp[e] = o; o += cnt[e]; }
    float s = 0.f;
    for (int e = 0; e < 8; e++) { float u = usage[e] * (1.f / T_TOK); s += u * u; }
    aux_out[0] = (float)NEXP * s;
  }
}

// gather x rows per expert into compact buffer
__global__ __launch_bounds__(256) void gather_x(const u16* __restrict__ xb,
                                                const int* __restrict__ cnt,
                                                const int* __restrict__ offp,
                                                const int* __restrict__ tok_list,
                                                u16* __restrict__ xg) {
  int e = blockIdx.y, i = blockIdx.x;
  if (i >= cnt[e]) return;
  int t = tok_list[e * 2048 + i];
  long j = offp[e] + i;
  ((uint2*)(xg + j * DMODEL))[threadIdx.x] =
      ((const uint2*)(xb + (long)t * DMODEL))[threadIdx.x];
}

// weighted expert-output combine + residual + LN2 -> final output
__global__ __launch_bounds__(256) void moe_ln2(
    const float* __restrict__ xf, const float* __restrict__ y,
    const int* __restrict__ offp, const int* __restrict__ tk_e,
    const int* __restrict__ tk_pos, const float* __restrict__ tk_prob,
    const float* __restrict__ g, const float* __restrict__ bb, float* __restrict__ out) {
  int t = blockIdx.x, tid = threadIdx.x;
  int e0 = tk_e[2 * t], e1 = tk_e[2 * t + 1];
  long j0 = (long)offp[e0] + tk_pos[2 * t];
  long j1 = (long)offp[e1] + tk_pos[2 * t + 1];
  float p0 = tk_prob[2 * t], p1 = tk_prob[2 * t + 1];
  float4 vx = ((const float4*)(xf + (long)t * DMODEL))[tid];
  float4 y0 = ((const float4*)(y + j0 * DMODEL))[tid];
  float4 y1 = ((const float4*)(y + j1 * DMODEL))[tid];
  float v0 = vx.x + p0 * y0.x + p1 * y1.x;
  float v1 = vx.y + p0 * y0.y + p1 * y1.y;
  float v2 = vx.z + p0 * y0.z + p1 * y1.z;
  float v3 = vx.w + p0 * y0.w + p1 * y1.w;
  float s = v0 + v1 + v2 + v3;
  float s2 = v0 * v0 + v1 * v1 + v2 * v2 + v3 * v3;
  __shared__ float sa[4], sb[4];
  for (int o = 32; o; o >>= 1) { s += __shfl_down(s, o); s2 += __shfl_down(s2, o); }
  int lane = tid & 63, w = tid >> 6;
  if (lane == 0) { sa[w] = s; sb[w] = s2; }
  __syncthreads();
  s = sa[0] + sa[1] + sa[2] + sa[3];
  s2 = sb[0] + sb[1] + sb[2] + sb[3];
  float mu = s * (1.f / DMODEL);
  float var = s2 * (1.f / DMODEL) - mu * mu;
  float rs = rsqrtf(var + LN_EPS);
  float4 gg = ((const float4*)g)[tid];
  float4 bv = ((const float4*)bb)[tid];
  float4 o;
  o.x = (v0 - mu) * rs * gg.x + bv.x;
  o.y = (v1 - mu) * rs * gg.y + bv.y;
  o.z = (v2 - mu) * rs * gg.z + bv.z;
  o.w = (v3 - mu) * rs * gg.w + bv.w;
  ((float4*)(out + (long)t * DMODEL))[tid] = o;
}

// ---------------------------------------------------------------------------
extern "C" void kernel_launch(void* const* d_in, const int* in_sizes, int n_in,
                              void* d_out, int out_size, void* d_ws, size_t ws_size,
                              hipStream_t stream) {
  const float* src  = (const float*)d_in[0];
  const float* inw  = (const float*)d_in[1];
  const float* inb  = (const float*)d_in[2];
  const float* outw = (const float*)d_in[3];
  const float* outb = (const float*)d_in[4];
  const float* gw   = (const float*)d_in[5];
  const float* gb   = (const float*)d_in[6];
  const float* w1   = (const float*)d_in[7];
  const float* b1   = (const float*)d_in[8];
  const float* w2   = (const float*)d_in[9];
  const float* b2   = (const float*)d_in[10];
  const float* g1   = (const float*)d_in[11];
  const float* bb1  = (const float*)d_in[12];
  const float* g2   = (const float*)d_in[13];
  const float* bb2  = (const float*)d_in[14];
  float* out = (float*)d_out;

  char* w = (char*)d_ws;
  auto alloc = [&](size_t bytes) {
    char* p = w;
    w += (bytes + 255) & ~(size_t)255;
    return p;
  };

  // control block first (single memset covers cnt+off+usage)
  int*   cnt     = (int*)alloc(8 * 4);
  int*   offp    = (int*)alloc(8 * 4);
  float* usage   = (float*)alloc(8 * 4);
  int*   tok_list= (int*)alloc((size_t)NEXP * 2048 * 4);
  int*   tk_e    = (int*)alloc((size_t)2 * T_TOK * 4);
  int*   tk_pos  = (int*)alloc((size_t)2 * T_TOK * 4);
  float* tk_prob = (float*)alloc((size_t)2 * T_TOK * 4);

  u16* src_bf  = (u16*)alloc((size_t)T_TOK * DMODEL * 2);
  u16* inw_bf  = (u16*)alloc((size_t)3 * DMODEL * DMODEL * 2);
  u16* outw_bf = (u16*)alloc((size_t)DMODEL * DMODEL * 2);
  u16* w1_bf   = (u16*)alloc((size_t)NEXP * FDIM * DMODEL * 2);
  u16* w2_bf   = (u16*)alloc((size_t)NEXP * DMODEL * FDIM * 2);
  u16* qkv_bf  = (u16*)alloc((size_t)T_TOK * 3 * DMODEL * 2);
  u16* vt_bf   = (u16*)alloc((size_t)T_TOK * DMODEL * 2);    // (B,H,HD,S)
  u16* o2_bf   = (u16*)alloc((size_t)T_TOK * DMODEL * 2);    // (B,S,D)
  float* attn_f= (float*)alloc((size_t)T_TOK * DMODEL * 4);
  float* x_f   = (float*)alloc((size_t)T_TOK * DMODEL * 4);
  u16* x_bf    = (u16*)alloc((size_t)T_TOK * DMODEL * 2);
  u16* xg_bf   = (u16*)alloc((size_t)2 * T_TOK * DMODEL * 2); // 4096 compact rows
  u16* h_bf    = (u16*)alloc((size_t)2 * T_TOK * FDIM * 2);
  float* y_f   = (float*)alloc((size_t)2 * T_TOK * DMODEL * 4);
  (void)ws_size; (void)n_in; (void)in_sizes; (void)out_size;

  hipMemsetAsync(cnt, 0, 3 * 256, stream);  // cnt, offp, usage regions

  // bf16 conversions
  cvt_bf16<<<(T_TOK * DMODEL / 4 + 255) / 256, 256, 0, stream>>>(src, src_bf, T_TOK * DMODEL / 4);
  cvt_bf16<<<(3 * DMODEL * DMODEL / 4 + 255) / 256, 256, 0, stream>>>(inw, inw_bf, 3L * DMODEL * DMODEL / 4);
  cvt_bf16<<<(DMODEL * DMODEL / 4 + 255) / 256, 256, 0, stream>>>(outw, outw_bf, (long)DMODEL * DMODEL / 4);
  cvt_bf16<<<(int)((long)NEXP * FDIM * DMODEL / 4 / 256), 256, 0, stream>>>(w1, w1_bf, (long)NEXP * FDIM * DMODEL / 4);
  cvt_bf16<<<(int)((long)NEXP * DMODEL * FDIM / 4 / 256), 256, 0, stream>>>(w2, w2_bf, (long)NEXP * DMODEL * FDIM / 4);

  // QKV projection: (2048x1024) @ (3072x1024)^T + b -> bf16
  gemm_bt<1, 0, 1><<<dim3(24, 16, 1), 256, 0, stream>>>(
      src_bf, DMODEL, inw_bf, DMODEL, 0, qkv_bf, 3 * DMODEL,
      inb, 0, T_TOK, 3 * DMODEL, DMODEL, nullptr, nullptr);

  transpose_v<<<dim3(16, 32), 256, 0, stream>>>(qkv_bf, vt_bf);

  // fused flash attention -> o2_bf (B,S,D)
  fused_attn<<<dim3(8, 32), 256, 0, stream>>>(qkv_bf, vt_bf, o2_bf);

  // output projection -> fp32
  gemm_bt<0, 0, 1><<<dim3(8, 16, 1), 256, 0, stream>>>(
      o2_bf, DMODEL, outw_bf, DMODEL, 0, attn_f, DMODEL,
      outb, 0, T_TOK, DMODEL, DMODEL, nullptr, nullptr);

  // residual + LN1
  add_ln<<<T_TOK, 256, 0, stream>>>(src, attn_f, g1, bb1, x_f, x_bf);

  // gate + routing
  gate_kernel<<<T_TOK / 4, 256, 0, stream>>>(x_f, gw, gb, cnt, tok_list,
                                             tk_e, tk_pos, tk_prob, usage);
  finalize_gate<<<1, 64, 0, stream>>>(cnt, offp, usage, out + (long)T_TOK * DMODEL);

  gather_x<<<dim3(2048, 8), 256, 0, stream>>>(x_bf, cnt, offp, tok_list, xg_bf);

  // FFN1 (grouped by expert, gelu fused) -> bf16
  gemm_bt<1, 1, 1><<<dim3(32, 16, 8), 256, 0, stream>>>(
      xg_bf, DMODEL, w1_bf, DMODEL, (long)FDIM * DMODEL, h_bf, FDIM,
      b1, FDIM, 0, FDIM, DMODEL, cnt, offp);

  // FFN2 (grouped) -> fp32
  gemm_bt<0, 0, 1><<<dim3(8, 16, 8), 256, 0, stream>>>(
      h_bf, FDIM, w2_bf, FDIM, (long)DMODEL * FDIM, y_f, DMODEL,
      b2, DMODEL, 0, DMODEL, FDIM, cnt, offp);

  // combine + residual + LN2 -> output
  moe_ln2<<<T_TOK, 256, 0, stream>>>(x_f, y_f, offp, tk_e, tk_pos, tk_prob,
                                     g2, bb2, out);
}

// Round 3
// 925.915 us; speedup vs baseline: 1.2065x; 1.0440x over previous
//
#include <hip/hip_runtime.h>
#include <stdint.h>
#include <stddef.h>

// Problem constants
#define T_TOK 2048     // B*S tokens
#define DMODEL 1024
#define NHEAD 16
#define HDIM 64
#define NEXP 8
#define FDIM 4096
#define SLEN 1024
#define NBATCH 2
#define LN_EPS 1e-5f

typedef unsigned short u16;
typedef __attribute__((ext_vector_type(8))) short s16x8;   // 8 bf16 MFMA frag
typedef __attribute__((ext_vector_type(4))) float f32x4;   // MFMA accumulator
typedef __attribute__((ext_vector_type(4))) unsigned short u16x4;
typedef __attribute__((ext_vector_type(8))) unsigned short u16x8;

typedef __attribute__((address_space(1))) void gvoid;      // global
typedef __attribute__((address_space(3))) void lvoid;      // LDS

__device__ __forceinline__ u16 f2bf(float x) {
  union { float f; unsigned int u; } v; v.f = x;
  unsigned int r = v.u + 0x7fffu + ((v.u >> 16) & 1u);  // RNE
  return (u16)(r >> 16);
}

// async global->LDS, 16B/lane. Dest MUST be wave-uniform base; HW adds lane*16.
__device__ __forceinline__ void gl_lds16(const u16* g, u16* lds_base) {
  __builtin_amdgcn_global_load_lds((gvoid*)g, (lvoid*)lds_base, 16, 0, 0);
}

// ---------------------------------------------------------------------------
// fp32 -> bf16 convert (named clones for profile attribution)
// ---------------------------------------------------------------------------
__device__ __forceinline__ void cvt_body(const float* __restrict__ x,
                                         u16* __restrict__ y, long n4) {
  long i = (long)blockIdx.x * 256 + threadIdx.x;
  if (i >= n4) return;
  float4 v = ((const float4*)x)[i];
  u16x4 o;
  o[0] = f2bf(v.x); o[1] = f2bf(v.y); o[2] = f2bf(v.z); o[3] = f2bf(v.w);
  ((u16x4*)y)[i] = o;
}
__global__ __launch_bounds__(256) void cvt_small(const float* x, u16* y, long n4) { cvt_body(x, y, n4); }
__global__ __launch_bounds__(256) void cvt_w1(const float* x, u16* y, long n4) { cvt_body(x, y, n4); }
__global__ __launch_bounds__(256) void cvt_w2(const float* x, u16* y, long n4) { cvt_body(x, y, n4); }

// ---------------------------------------------------------------------------
// GEMM body: C = act(A @ B^T + bias), BN=128 fixed, BM in {64,128}.
// A: Mloc x K (lda), B: N x K (ldb), C: Mloc x N (ldc elems).
// K-range [k0start, k0start+Kc). bias: runtime nullptr -> skip.
// LDS XOR-swizzled granules; global_load_lds with wave-uniform dest base.
// ---------------------------------------------------------------------------
template<int BM, int OUTBF, int DOGELU>
__device__ __forceinline__ void gemm_body(
    const u16* __restrict__ A, long lda,
    const u16* __restrict__ Bp, long ldb,
    char* __restrict__ C, long ldc,
    const float* __restrict__ bias,
    int Mloc, int k0start, int Kc, int m0, int n0) {
  __shared__ u16 As[BM][64];
  __shared__ u16 Bs[128][64];

  int tid = threadIdx.x;
  int lane = tid & 63, w = tid >> 6;
  int lrow = lane >> 3;                       // 0..7
  int sg8 = ((lane & 7) ^ lrow) * 8;          // swizzled source granule (elems)
  int q = lane >> 4, rr = lane & 15;
  constexpr int SM = BM / 32;                 // frags per wave in M
  int wm = (w & 1) * (BM / 2), wn = (w >> 1) * 64;

  f32x4 acc[SM][4];
  for (int i = 0; i < SM; i++)
    for (int j = 0; j < 4; j++)
      for (int r = 0; r < 4; r++) acc[i][j][r] = 0.f;

  for (int k0 = k0start; k0 < k0start + Kc; k0 += 64) {
    __syncthreads();
    for (int p = 0; p < BM / 32; p++) {
      int rb = p * 32 + w * 8;
      int gr = m0 + rb + lrow; if (gr > Mloc - 1) gr = Mloc - 1;   // M-tail clamp
      gl_lds16(A + (long)gr * lda + k0 + sg8, &As[rb][0]);
    }
    for (int p = 0; p < 4; p++) {
      int rb = p * 32 + w * 8;
      gl_lds16(Bp + (long)(n0 + rb + lrow) * ldb + k0 + sg8, &Bs[rb][0]);
    }
    __syncthreads();
    for (int kk = 0; kk < 2; kk++) {
      int slot = (((kk * 4 + q) ^ (rr & 7)) * 8);
      s16x8 af[SM], bfv[4];
      for (int i = 0; i < SM; i++) af[i] = *(const s16x8*)&As[wm + i * 16 + rr][slot];
      for (int j = 0; j < 4; j++) bfv[j] = *(const s16x8*)&Bs[wn + j * 16 + rr][slot];
      for (int i = 0; i < SM; i++)
        for (int j = 0; j < 4; j++)
          acc[i][j] = __builtin_amdgcn_mfma_f32_16x16x32_bf16(af[i], bfv[j], acc[i][j], 0, 0, 0);
    }
  }

  for (int i = 0; i < SM; i++) {
    for (int j = 0; j < 4; j++) {
      int col = n0 + wn + j * 16 + rr;
      float bv = bias ? bias[col - n0 + n0] : 0.f;  // bias indexed by global col
      if (bias) bv = bias[col];
      for (int r = 0; r < 4; r++) {
        int row = m0 + wm + i * 16 + q * 4 + r;
        if (row < Mloc) {
          float v = acc[i][j][r] + bv;
          if (DOGELU) v = 0.5f * v * (1.f + erff(v * 0.70710678118f));
          if (OUTBF) ((u16*)C)[(long)row * ldc + col] = f2bf(v);
          else ((float*)C)[(long)row * ldc + col] = v;
        }
      }
    }
  }
}

// ---- named GEMM wrappers (distinct kernels for rocprof attribution) -------
__global__ __launch_bounds__(256) void k_qkv(const u16* __restrict__ A,
                                             const u16* __restrict__ B,
                                             u16* __restrict__ C,
                                             const float* __restrict__ bias) {
  gemm_body<64, 1, 0>(A, DMODEL, B, DMODEL, (char*)C, 3 * DMODEL, bias,
                      T_TOK, 0, DMODEL, blockIdx.y * 64, blockIdx.x * 128);
}

// out-projection, split-K=2: z picks K-half, writes partial buffer z
__global__ __launch_bounds__(256) void k_outp(const u16* __restrict__ A,
                                              const u16* __restrict__ B,
                                              float* __restrict__ Cpart) {
  int z = blockIdx.z;
  char* C = (char*)(Cpart + (long)z * T_TOK * DMODEL);
  gemm_body<64, 0, 0>(A, DMODEL, B, DMODEL, C, DMODEL, nullptr,
                      T_TOK, z * 512, 512, blockIdx.y * 64, blockIdx.x * 128);
}

__global__ __launch_bounds__(256) void k_ffn1(const u16* __restrict__ Ag,
                                              const u16* __restrict__ Bg,
                                              u16* __restrict__ Cg,
                                              const float* __restrict__ biasg,
                                              const int* __restrict__ cntp,
                                              const int* __restrict__ offp) {
  int z = blockIdx.z;
  int Mloc = cntp[z];
  int m0 = blockIdx.y * 128;
  if (m0 >= Mloc) return;
  long o = offp[z];
  gemm_body<128, 1, 1>(Ag + o * DMODEL, DMODEL,
                       Bg + (long)z * FDIM * DMODEL, DMODEL,
                       (char*)(Cg + o * FDIM), FDIM,
                       biasg + (long)z * FDIM,
                       Mloc, 0, DMODEL, m0, blockIdx.x * 128);
}

__global__ __launch_bounds__(256) void k_ffn2(const u16* __restrict__ Ag,
                                              const u16* __restrict__ Bg,
                                              float* __restrict__ Cg,
                                              const float* __restrict__ biasg,
                                              const int* __restrict__ cntp,
                                              const int* __restrict__ offp) {
  int z = blockIdx.z;
  int Mloc = cntp[z];
  int m0 = blockIdx.y * 64;
  if (m0 >= Mloc) return;
  long o = offp[z];
  gemm_body<64, 0, 0>(Ag + o * FDIM, FDIM,
                      Bg + (long)z * DMODEL * FDIM, FDIM,
                      (char*)(Cg + o * DMODEL), DMODEL,
                      biasg + (long)z * DMODEL,
                      Mloc, 0, FDIM, m0, blockIdx.x * 128);
}

// ---------------------------------------------------------------------------
// V part of qkv -> Vt (B,H,HD,S) bf16 (transposed via LDS tile)
// ---------------------------------------------------------------------------
__global__ __launch_bounds__(256) void transpose_v(const u16* __restrict__ qkv,
                                                   u16* __restrict__ vt) {
  __shared__ u16 tile[64][65];
  int s0 = blockIdx.x * 64, bh = blockIdx.y;
  int b = bh >> 4, h = bh & 15;
  int r = threadIdx.x >> 3, c = (threadIdx.x & 7) * 8;
  for (int p = 0; p < 64; p += 32) {
    u16x8 v = *(const u16x8*)&qkv[(long)(b * SLEN + s0 + p + r) * 3072 + 2048 + h * 64 + c];
    for (int j = 0; j < 8; j++) tile[p + r][c + j] = v[j];
  }
  __syncthreads();
  for (int p = 0; p < 64; p += 32) {
    int d = p + r;
    u16x8 v;
    for (int j = 0; j < 8; j++) v[j] = tile[c + j][d];
    *(u16x8*)&vt[((long)bh * 64 + d) * SLEN + s0 + c] = v;
  }
}

// ---------------------------------------------------------------------------
// Fused flash attention: per (q-tile 128, b*h) block. Writes (B,S,D) bf16.
// ---------------------------------------------------------------------------
__global__ __launch_bounds__(256) void fused_attn(const u16* __restrict__ qkv,
                                                  const u16* __restrict__ vt,
                                                  u16* __restrict__ o2) {
  __shared__ u16 Qs[128][64];   // swizzled
  __shared__ u16 Ks[64][64];    // swizzled
  __shared__ u16 Vs[64][64];    // swizzled (rows = head-dim d, cols = 64 keys)
  __shared__ u16 Ps[128][72];   // padded

  int qt = blockIdx.x, bh = blockIdx.y;
  int b = bh >> 4, h = bh & 15;
  const u16* base = qkv + (long)b * SLEN * 3072 + h * 64;
  const u16* vbase = vt + (long)bh * HDIM * SLEN;

  int tid = threadIdx.x, lane = tid & 63, w = tid >> 6;
  int lrow = lane >> 3;
  int sg8 = ((lane & 7) ^ lrow) * 8;
  int q = lane >> 4, rr = lane & 15;
  int wm = w * 32;

  // stage Q once
  for (int p = 0; p < 4; p++) {
    int rb = p * 32 + w * 8;
    gl_lds16(base + (long)(qt * 128 + rb + lrow) * 3072 + sg8, &Qs[rb][0]);
  }

  f32x4 O[2][4];
  float mi[2][4], li[2][4];
  for (int i = 0; i < 2; i++)
    for (int r = 0; r < 4; r++) { mi[i][r] = -1e30f; li[i][r] = 0.f; }
  for (int i = 0; i < 2; i++)
    for (int jn = 0; jn < 4; jn++)
      for (int r = 0; r < 4; r++) O[i][jn][r] = 0.f;

  for (int kt = 0; kt < 16; kt++) {
    __syncthreads();
    for (int p = 0; p < 2; p++) {
      int rb = p * 32 + w * 8;
      gl_lds16(base + (long)(kt * 64 + rb + lrow) * 3072 + 1024 + sg8, &Ks[rb][0]);
      gl_lds16(vbase + (long)(rb + lrow) * SLEN + kt * 64 + sg8, &Vs[rb][0]);
    }
    __syncthreads();

    // S = Q @ K^T
    f32x4 S[2][4];
    for (int i = 0; i < 2; i++)
      for (int j = 0; j < 4; j++)
        for (int r = 0; r < 4; r++) S[i][j][r] = 0.f;
    for (int ks = 0; ks < 2; ks++) {
      int slot = (((ks * 4 + q) ^ (rr & 7)) * 8);
      s16x8 aq0 = *(const s16x8*)&Qs[wm + rr][slot];
      s16x8 aq1 = *(const s16x8*)&Qs[wm + 16 + rr][slot];
      for (int j = 0; j < 4; j++) {
        s16x8 bk = *(const s16x8*)&Ks[j * 16 + rr][slot];
        S[0][j] = __builtin_amdgcn_mfma_f32_16x16x32_bf16(aq0, bk, S[0][j], 0, 0, 0);
        S[1][j] = __builtin_amdgcn_mfma_f32_16x16x32_bf16(aq1, bk, S[1][j], 0, 0, 0);
      }
    }

    // online softmax
    for (int i = 0; i < 2; i++) {
      for (int r = 0; r < 4; r++) {
        float mx = -1e30f;
        for (int j = 0; j < 4; j++) mx = fmaxf(mx, S[i][j][r]);
        for (int o = 1; o < 16; o <<= 1) mx = fmaxf(mx, __shfl_xor(mx, o));
        mx *= 0.125f;
        float mnew = fmaxf(mi[i][r], mx);
        float al = __expf(mi[i][r] - mnew);
        mi[i][r] = mnew;
        float ps = 0.f;
        for (int j = 0; j < 4; j++) {
          float e = __expf(S[i][j][r] * 0.125f - mnew);
          S[i][j][r] = e;
          ps += e;
        }
        for (int o = 1; o < 16; o <<= 1) ps += __shfl_xor(ps, o);
        li[i][r] = li[i][r] * al + ps;
        for (int jn = 0; jn < 4; jn++) O[i][jn][r] *= al;
      }
    }

    // P -> LDS (C-layout scatter)
    for (int i = 0; i < 2; i++)
      for (int j = 0; j < 4; j++)
        for (int r = 0; r < 4; r++)
          Ps[wm + i * 16 + q * 4 + r][j * 16 + rr] = f2bf(S[i][j][r]);
    __syncthreads();

    // O += P @ V
    for (int ks = 0; ks < 2; ks++) {
      s16x8 ap0 = *(const s16x8*)&Ps[wm + rr][ks * 32 + q * 8];
      s16x8 ap1 = *(const s16x8*)&Ps[wm + 16 + rr][ks * 32 + q * 8];
      int slot = (((ks * 4 + q) ^ (rr & 7)) * 8);
      for (int jn = 0; jn < 4; jn++) {
        s16x8 bv = *(const s16x8*)&Vs[jn * 16 + rr][slot];
        O[0][jn] = __builtin_amdgcn_mfma_f32_16x16x32_bf16(ap0, bv, O[0][jn], 0, 0, 0);
        O[1][jn] = __builtin_amdgcn_mfma_f32_16x16x32_bf16(ap1, bv, O[1][jn], 0, 0, 0);
      }
    }
  }

  for (int i = 0; i < 2; i++)
    for (int r = 0; r < 4; r++) {
      float inv = 1.f / li[i][r];
      int s = qt * 128 + wm + i * 16 + q * 4 + r;
      long rowp = ((long)(b * SLEN + s)) * DMODEL + h * 64;
      for (int jn = 0; jn < 4; jn++)
        o2[rowp + jn * 16 + rr] = f2bf(O[i][jn][r] * inv);
    }
}

// ---------------------------------------------------------------------------
// residual add (+out-proj bias, 2 split-K partials) + LayerNorm -> fp32+bf16
// ---------------------------------------------------------------------------
__global__ __launch_bounds__(256) void add_ln(const float* __restrict__ a,
                                              const float* __restrict__ p0,
                                              const float* __restrict__ p1,
                                              const float* __restrict__ ob,
                                              const float* __restrict__ g,
                                              const float* __restrict__ bb,
                                              float* __restrict__ xf, u16* __restrict__ xb) {
  int t = blockIdx.x, tid = threadIdx.x;
  float4 va = ((const float4*)(a + (long)t * DMODEL))[tid];
  float4 v0v = ((const float4*)(p0 + (long)t * DMODEL))[tid];
  float4 v1v = ((const float4*)(p1 + (long)t * DMODEL))[tid];
  float4 vo = ((const float4*)ob)[tid];
  float v0 = va.x + v0v.x + v1v.x + vo.x;
  float v1 = va.y + v0v.y + v1v.y + vo.y;
  float v2 = va.z + v0v.z + v1v.z + vo.z;
  float v3 = va.w + v0v.w + v1v.w + vo.w;
  float s = v0 + v1 + v2 + v3;
  float s2 = v0 * v0 + v1 * v1 + v2 * v2 + v3 * v3;
  __shared__ float sa[4], sb[4];
  for (int o = 32; o; o >>= 1) { s += __shfl_down(s, o); s2 += __shfl_down(s2, o); }
  int lane = tid & 63, w = tid >> 6;
  if (lane == 0) { sa[w] = s; sb[w] = s2; }
  __syncthreads();
  s = sa[0] + sa[1] + sa[2] + sa[3];
  s2 = sb[0] + sb[1] + sb[2] + sb[3];
  float mu = s * (1.f / DMODEL);
  float var = s2 * (1.f / DMODEL) - mu * mu;
  float rs = rsqrtf(var + LN_EPS);
  float4 gg = ((const float4*)g)[tid];
  float4 bv = ((const float4*)bb)[tid];
  float4 o;
  o.x = (v0 - mu) * rs * gg.x + bv.x;
  o.y = (v1 - mu) * rs * gg.y + bv.y;
  o.z = (v2 - mu) * rs * gg.z + bv.z;
  o.w = (v3 - mu) * rs * gg.w + bv.w;
  ((float4*)(xf + (long)t * DMODEL))[tid] = o;
  u16x4 obv;
  obv[0] = f2bf(o.x); obv[1] = f2bf(o.y); obv[2] = f2bf(o.z); obv[3] = f2bf(o.w);
  ((u16x4*)(xb + (long)t * DMODEL))[tid] = obv;
}

// ---------------------------------------------------------------------------
// Gate: logits, full softmax (usage/aux), top-2 routing lists
// ---------------------------------------------------------------------------
__global__ __launch_bounds__(256) void gate_kernel(
    const float* __restrict__ xf, const float* __restrict__ gw, const float* __restrict__ gb,
    int* __restrict__ cnt, int* __restrict__ tok_list,
    int* __restrict__ tk_e, int* __restrict__ tk_pos, float* __restrict__ tk_prob,
    float* __restrict__ usage) {
  int wid = threadIdx.x >> 6, lane = threadIdx.x & 63;
  int t = blockIdx.x * 4 + wid;
  float xv[16];
  for (int j = 0; j < 16; j++) xv[j] = xf[(long)t * DMODEL + j * 64 + lane];
  float l[8];
  for (int e = 0; e < 8; e++) {
    float d = 0.f;
    for (int j = 0; j < 16; j++) d += xv[j] * gw[e * DMODEL + j * 64 + lane];
    for (int o = 32; o; o >>= 1) d += __shfl_down(d, o);
    l[e] = d;  // valid on lane 0 only
  }
  __shared__ float us[8];
  if (threadIdx.x < 8) us[threadIdx.x] = 0.f;
  __syncthreads();
  if (lane == 0) {
    float mx = -1e30f;
    for (int e = 0; e < 8; e++) { l[e] += gb[e]; mx = fmaxf(mx, l[e]); }
    float ex[8], sum = 0.f;
    for (int e = 0; e < 8; e++) { ex[e] = expf(l[e] - mx); sum += ex[e]; }
    float inv = 1.f / sum;
    for (int e = 0; e < 8; e++) atomicAdd(&us[e], ex[e] * inv);
    int i1 = 0;
    for (int e = 1; e < 8; e++) if (l[e] > l[i1]) i1 = e;
    int i2 = (i1 == 0) ? 1 : 0;
    for (int e = 0; e < 8; e++) if (e != i1 && l[e] > l[i2]) i2 = e;
    float bb = expf(l[i2] - l[i1]);
    float p1 = 1.f / (1.f + bb), p2 = bb / (1.f + bb);
    int pos1 = atomicAdd(&cnt[i1], 1);
    tok_list[i1 * 2048 + pos1] = t;
    tk_e[2 * t] = i1; tk_pos[2 * t] = pos1; tk_prob[2 * t] = p1;
    int pos2 = atomicAdd(&cnt[i2], 1);
    tok_list[i2 * 2048 + pos2] = t;
    tk_e[2 * t + 1] = i2; tk_pos[2 * t + 1] = pos2; tk_prob[2 * t + 1] = p2;
  }
  __syncthreads();
  if (threadIdx.x < 8) atomicAdd(&usage[threadIdx.x], us[threadIdx.x]);
}

__global__ void finalize_gate(const int* __restrict__ cnt, int* __restrict__ offp,
                              const float* __restrict__ usage, float* __restrict__ aux_out) {
  if (threadIdx.x == 0) {
    int o = 0;
    for (int e = 0; e < 8; e++) { offp[e] = o; o += cnt[e]; }
    float s = 0.f;
    for (int e = 0; e < 8; e++) { float u = usage[e] * (1.f / T_TOK); s += u * u; }
    aux_out[0] = (float)NEXP * s;
  }
}

// gather x rows per expert into compact buffer
__global__ __launch_bounds__(256) void gather_x(const u16* __restrict__ xb,
                                                const int* __restrict__ cnt,
                                                const int* __restrict__ offp,
                                                const int* __restrict__ tok_list,
                                                u16* __restrict__ xg) {
  int e = blockIdx.y, i = blockIdx.x;
  if (i >= cnt[e]) return;
  int t = tok_list[e * 2048 + i];
  long j = offp[e] + i;
  ((uint2*)(xg + j * DMODEL))[threadIdx.x] =
      ((const uint2*)(xb + (long)t * DMODEL))[threadIdx.x];
}

// weighted expert-output combine + residual + LN2 -> final output
__global__ __launch_bounds__(256) void moe_ln2(
    const float* __restrict__ xf, const float* __restrict__ y,
    const int* __restrict__ offp, const int* __restrict__ tk_e,
    const int* __restrict__ tk_pos, const float* __restrict__ tk_prob,
    const float* __restrict__ g, const float* __restrict__ bb, float* __restrict__ out) {
  int t = blockIdx.x, tid = threadIdx.x;
  int e0 = tk_e[2 * t], e1 = tk_e[2 * t + 1];
  long j0 = (long)offp[e0] + tk_pos[2 * t];
  long j1 = (long)offp[e1] + tk_pos[2 * t + 1];
  float p0 = tk_prob[2 * t], p1 = tk_prob[2 * t + 1];
  float4 vx = ((const float4*)(xf + (long)t * DMODEL))[tid];
  float4 y0 = ((const float4*)(y + j0 * DMODEL))[tid];
  float4 y1 = ((const float4*)(y + j1 * DMODEL))[tid];
  float v0 = vx.x + p0 * y0.x + p1 * y1.x;
  float v1 = vx.y + p0 * y0.y + p1 * y1.y;
  float v2 = vx.z + p0 * y0.z + p1 * y1.z;
  float v3 = vx.w + p0 * y0.w + p1 * y1.w;
  float s = v0 + v1 + v2 + v3;
  float s2 = v0 * v0 + v1 * v1 + v2 * v2 + v3 * v3;
  __shared__ float sa[4], sb[4];
  for (int o = 32; o; o >>= 1) { s += __shfl_down(s, o); s2 += __shfl_down(s2, o); }
  int lane = tid & 63, w = tid >> 6;
  if (lane == 0) { sa[w] = s; sb[w] = s2; }
  __syncthreads();
  s = sa[0] + sa[1] + sa[2] + sa[3];
  s2 = sb[0] + sb[1] + sb[2] + sb[3];
  float mu = s * (1.f / DMODEL);
  float var = s2 * (1.f / DMODEL) - mu * mu;
  float rs = rsqrtf(var + LN_EPS);
  float4 gg = ((const float4*)g)[tid];
  float4 bv = ((const float4*)bb)[tid];
  float4 o;
  o.x = (v0 - mu) * rs * gg.x + bv.x;
  o.y = (v1 - mu) * rs * gg.y + bv.y;
  o.z = (v2 - mu) * rs * gg.z + bv.z;
  o.w = (v3 - mu) * rs * gg.w + bv.w;
  ((float4*)(out + (long)t * DMODEL))[tid] = o;
}

// ---------------------------------------------------------------------------
extern "C" void kernel_launch(void* const* d_in, const int* in_sizes, int n_in,
                              void* d_out, int out_size, void* d_ws, size_t ws_size,
                              hipStream_t stream) {
  const float* src  = (const float*)d_in[0];
  const float* inw  = (const float*)d_in[1];
  const float* inb  = (const float*)d_in[2];
  const float* outw = (const float*)d_in[3];
  const float* outb = (const float*)d_in[4];
  const float* gw   = (const float*)d_in[5];
  const float* gb   = (const float*)d_in[6];
  const float* w1   = (const float*)d_in[7];
  const float* b1   = (const float*)d_in[8];
  const float* w2   = (const float*)d_in[9];
  const float* b2   = (const float*)d_in[10];
  const float* g1   = (const float*)d_in[11];
  const float* bb1  = (const float*)d_in[12];
  const float* g2   = (const float*)d_in[13];
  const float* bb2  = (const float*)d_in[14];
  float* out = (float*)d_out;

  char* w = (char*)d_ws;
  auto alloc = [&](size_t bytes) {
    char* p = w;
    w += (bytes + 255) & ~(size_t)255;
    return p;
  };

  int*   cnt     = (int*)alloc(8 * 4);
  int*   offp    = (int*)alloc(8 * 4);
  float* usage   = (float*)alloc(8 * 4);
  int*   tok_list= (int*)alloc((size_t)NEXP * 2048 * 4);
  int*   tk_e    = (int*)alloc((size_t)2 * T_TOK * 4);
  int*   tk_pos  = (int*)alloc((size_t)2 * T_TOK * 4);
  float* tk_prob = (float*)alloc((size_t)2 * T_TOK * 4);

  u16* src_bf  = (u16*)alloc((size_t)T_TOK * DMODEL * 2);
  u16* inw_bf  = (u16*)alloc((size_t)3 * DMODEL * DMODEL * 2);
  u16* outw_bf = (u16*)alloc((size_t)DMODEL * DMODEL * 2);
  u16* w1_bf   = (u16*)alloc((size_t)NEXP * FDIM * DMODEL * 2);
  u16* w2_bf   = (u16*)alloc((size_t)NEXP * DMODEL * FDIM * 2);
  u16* qkv_bf  = (u16*)alloc((size_t)T_TOK * 3 * DMODEL * 2);
  u16* vt_bf   = (u16*)alloc((size_t)T_TOK * DMODEL * 2);    // (B,H,HD,S)
  u16* o2_bf   = (u16*)alloc((size_t)T_TOK * DMODEL * 2);    // (B,S,D)
  float* attn_p= (float*)alloc((size_t)2 * T_TOK * DMODEL * 4);  // 2 split-K partials
  float* x_f   = (float*)alloc((size_t)T_TOK * DMODEL * 4);
  u16* x_bf    = (u16*)alloc((size_t)T_TOK * DMODEL * 2);
  u16* xg_bf   = (u16*)alloc((size_t)2 * T_TOK * DMODEL * 2);
  u16* h_bf    = (u16*)alloc((size_t)2 * T_TOK * FDIM * 2);
  float* y_f   = (float*)alloc((size_t)2 * T_TOK * DMODEL * 4);
  (void)ws_size; (void)n_in; (void)in_sizes; (void)out_size;

  hipMemsetAsync(cnt, 0, 3 * 256, stream);  // cnt, offp, usage regions

  // bf16 conversions
  cvt_small<<<(T_TOK * DMODEL / 4 + 255) / 256, 256, 0, stream>>>(src, src_bf, T_TOK * DMODEL / 4);
  cvt_small<<<(3 * DMODEL * DMODEL / 4 + 255) / 256, 256, 0, stream>>>(inw, inw_bf, 3L * DMODEL * DMODEL / 4);
  cvt_small<<<(DMODEL * DMODEL / 4 + 255) / 256, 256, 0, stream>>>(outw, outw_bf, (long)DMODEL * DMODEL / 4);
  cvt_w1<<<(int)((long)NEXP * FDIM * DMODEL / 4 / 256), 256, 0, stream>>>(w1, w1_bf, (long)NEXP * FDIM * DMODEL / 4);
  cvt_w2<<<(int)((long)NEXP * DMODEL * FDIM / 4 / 256), 256, 0, stream>>>(w2, w2_bf, (long)NEXP * DMODEL * FDIM / 4);

  // QKV projection: (2048x1024) @ (3072x1024)^T + b -> bf16
  k_qkv<<<dim3(24, 32), 256, 0, stream>>>(src_bf, inw_bf, qkv_bf, inb);

  transpose_v<<<dim3(16, 32), 256, 0, stream>>>(qkv_bf, vt_bf);

  // fused flash attention -> o2_bf (B,S,D)
  fused_attn<<<dim3(8, 32), 256, 0, stream>>>(qkv_bf, vt_bf, o2_bf);

  // output projection, split-K=2 -> two fp32 partials (bias folded into add_ln)
  k_outp<<<dim3(8, 32, 2), 256, 0, stream>>>(o2_bf, outw_bf, attn_p);

  // residual + out-proj bias + LN1
  add_ln<<<T_TOK, 256, 0, stream>>>(src, attn_p, attn_p + (long)T_TOK * DMODEL,
                                    outb, g1, bb1, x_f, x_bf);

  // gate + routing
  gate_kernel<<<T_TOK / 4, 256, 0, stream>>>(x_f, gw, gb, cnt, tok_list,
                                             tk_e, tk_pos, tk_prob, usage);
  finalize_gate<<<1, 64, 0, stream>>>(cnt, offp, usage, out + (long)T_TOK * DMODEL);

  gather_x<<<dim3(2048, 8), 256, 0, stream>>>(x_bf, cnt, offp, tok_list, xg_bf);

  // FFN1 (grouped, gelu fused) -> bf16
  k_ffn1<<<dim3(32, 16, 8), 256, 0, stream>>>(xg_bf, w1_bf, h_bf, b1, cnt, offp);

  // FFN2 (grouped) -> fp32
  k_ffn2<<<dim3(8, 32, 8), 256, 0, stream>>>(h_bf, w2_bf, y_f, b2, cnt, offp);

  // combine + residual + LN2 -> output
  moe_ln2<<<T_TOK, 256, 0, stream>>>(x_f, y_f, offp, tk_e, tk_pos, tk_prob,
                                     g2, bb2, out);
}

// Round 4
// 738.027 us; speedup vs baseline: 1.5136x; 1.2546x over previous
//
#include <hip/hip_runtime.h>
#include <stdint.h>
#include <stddef.h>

// Problem constants
#define T_TOK 2048     // B*S tokens
#define DMODEL 1024
#define NHEAD 16
#define HDIM 64
#define NEXP 8
#define FDIM 4096
#define SLEN 1024
#define NBATCH 2
#define LN_EPS 1e-5f

typedef unsigned short u16;
typedef __attribute__((ext_vector_type(8))) short s16x8;   // 8 bf16 MFMA frag
typedef __attribute__((ext_vector_type(4))) float f32x4;   // MFMA accumulator
typedef __attribute__((ext_vector_type(4))) unsigned short u16x4;
typedef __attribute__((ext_vector_type(8))) unsigned short u16x8;

typedef __attribute__((address_space(1))) void gvoid;      // global
typedef __attribute__((address_space(3))) void lvoid;      // LDS

__device__ __forceinline__ u16 f2bf(float x) {
  union { float f; unsigned int u; } v; v.f = x;
  unsigned int r = v.u + 0x7fffu + ((v.u >> 16) & 1u);  // RNE
  return (u16)(r >> 16);
}

// async global->LDS, 16B/lane. Dest is wave-uniform base; HW adds lane*16.
__device__ __forceinline__ void gl_lds16(const u16* g, u16* lds_base) {
  __builtin_amdgcn_global_load_lds((gvoid*)g, (lvoid*)lds_base, 16, 0, 0);
}

// ---------------------------------------------------------------------------
// fp32 -> bf16 convert (named clones for profile attribution)
// ---------------------------------------------------------------------------
__device__ __forceinline__ void cvt_body(const float* __restrict__ x,
                                         u16* __restrict__ y, long n4) {
  long i = (long)blockIdx.x * 256 + threadIdx.x;
  if (i >= n4) return;
  float4 v = ((const float4*)x)[i];
  u16x4 o;
  o[0] = f2bf(v.x); o[1] = f2bf(v.y); o[2] = f2bf(v.z); o[3] = f2bf(v.w);
  ((u16x4*)y)[i] = o;
}
__global__ __launch_bounds__(256) void cvt_small(const float* x, u16* y, long n4) { cvt_body(x, y, n4); }
__global__ __launch_bounds__(256) void cvt_w1(const float* x, u16* y, long n4) { cvt_body(x, y, n4); }
__global__ __launch_bounds__(256) void cvt_w2(const float* x, u16* y, long n4) { cvt_body(x, y, n4); }

// ---------------------------------------------------------------------------
// Pipelined GEMM body: C = act(A @ B^T + bias), BN=128, BM in {64,128}.
// Double-buffered LDS, prefetch distance 2, raw s_barrier + partial vmcnt
// waits (never vmcnt(0) mid-loop) so tile k+1's DMA stays in flight while
// tile k is computed — the AITER-style K-loop the m97 2-barrier shape can't
// express.
// ---------------------------------------------------------------------------
template<int BM, int OUTBF, int DOGELU>
__device__ __forceinline__ void gemm_body(
    const u16* __restrict__ A, long lda,
    const u16* __restrict__ Bp, long ldb,
    char* __restrict__ C, long ldc,
    const float* __restrict__ bias,
    int Mloc, int k0start, int Kc, int m0, int n0) {
  __shared__ u16 As[2][BM][64];
  __shared__ u16 Bs[2][128][64];
  constexpr int SM = BM / 32;           // M-frags per wave
  constexpr int LPI = BM / 32 + 4;      // gl_lds insts per wave per tile

  int tid = threadIdx.x;
  int lane = tid & 63, w = tid >> 6;
  int lrow = lane >> 3;                 // 0..7
  int sg8 = ((lane & 7) ^ lrow) * 8;    // XOR-swizzled source granule
  int q = lane >> 4, rr = lane & 15;
  int wm = (w & 1) * (BM / 2), wn = (w >> 1) * 64;
  int NIT = Kc >> 6;

  auto issue = [&](int kt, int b) {
    int k0 = k0start + (kt << 6);
    for (int p = 0; p < BM / 32; p++) {
      int rb = p * 32 + w * 8;
      int gr = m0 + rb + lrow; if (gr > Mloc - 1) gr = Mloc - 1;   // M-tail clamp
      gl_lds16(A + (long)gr * lda + k0 + sg8, &As[b][rb][0]);
    }
    for (int p = 0; p < 4; p++) {
      int rb = p * 32 + w * 8;
      gl_lds16(Bp + (long)(n0 + rb + lrow) * ldb + k0 + sg8, &Bs[b][rb][0]);
    }
  };

  f32x4 acc[SM][4];
  for (int i = 0; i < SM; i++)
    for (int j = 0; j < 4; j++)
      for (int r = 0; r < 4; r++) acc[i][j][r] = 0.f;

  issue(0, 0);
  if (NIT > 1) issue(1, 1);

  int slot0 = ((q ^ (rr & 7)) * 8);           // kk=0 swizzled slot
  int slot1 = (((4 + q) ^ (rr & 7)) * 8);     // kk=1

  for (int kt = 0; kt < NIT; kt++) {
    int b = kt & 1;
    // wait for tile kt only; tile kt+1's LPI loads remain outstanding
    if (kt + 1 < NIT)
      asm volatile("s_waitcnt vmcnt(%0)" :: "i"(LPI) : "memory");
    else
      asm volatile("s_waitcnt vmcnt(0)" ::: "memory");
    asm volatile("s_barrier" ::: "memory");

    s16x8 a0[SM], a1[SM], b0[4], b1[4];
    for (int i = 0; i < SM; i++) {
      a0[i] = *(const s16x8*)&As[b][wm + i * 16 + rr][slot0];
      a1[i] = *(const s16x8*)&As[b][wm + i * 16 + rr][slot1];
    }
    for (int j = 0; j < 4; j++) {
      b0[j] = *(const s16x8*)&Bs[b][wn + j * 16 + rr][slot0];
      b1[j] = *(const s16x8*)&Bs[b][wn + j * 16 + rr][slot1];
    }
    asm volatile("s_waitcnt lgkmcnt(0)" ::: "memory");  // frags in regs
    asm volatile("s_barrier" ::: "memory");             // all waves done reading buf b
    if (kt + 2 < NIT) issue(kt + 2, b);                 // overwrite buf b (visible at kt+2)

    for (int i = 0; i < SM; i++)
      for (int j = 0; j < 4; j++) {
        acc[i][j] = __builtin_amdgcn_mfma_f32_16x16x32_bf16(a0[i], b0[j], acc[i][j], 0, 0, 0);
        acc[i][j] = __builtin_amdgcn_mfma_f32_16x16x32_bf16(a1[i], b1[j], acc[i][j], 0, 0, 0);
      }
  }

  for (int i = 0; i < SM; i++) {
    for (int j = 0; j < 4; j++) {
      int col = n0 + wn + j * 16 + rr;
      float bv = bias ? bias[col] : 0.f;
      for (int r = 0; r < 4; r++) {
        int row = m0 + wm + i * 16 + q * 4 + r;
        if (row < Mloc) {
          float v = acc[i][j][r] + bv;
          if (DOGELU) v = 0.5f * v * (1.f + erff(v * 0.70710678118f));
          if (OUTBF) ((u16*)C)[(long)row * ldc + col] = f2bf(v);
          else ((float*)C)[(long)row * ldc + col] = v;
        }
      }
    }
  }
}

// ---- named GEMM wrappers (distinct kernels for rocprof attribution) -------
__global__ __launch_bounds__(256) void k_qkv(const u16* __restrict__ A,
                                             const u16* __restrict__ B,
                                             u16* __restrict__ C,
                                             const float* __restrict__ bias) {
  gemm_body<64, 1, 0>(A, DMODEL, B, DMODEL, (char*)C, 3 * DMODEL, bias,
                      T_TOK, 0, DMODEL, blockIdx.y * 64, blockIdx.x * 128);
}

// out-projection, split-K=2: z picks K-half, writes partial buffer z
__global__ __launch_bounds__(256) void k_outp(const u16* __restrict__ A,
                                              const u16* __restrict__ B,
                                              float* __restrict__ Cpart) {
  int z = blockIdx.z;
  char* C = (char*)(Cpart + (long)z * T_TOK * DMODEL);
  gemm_body<64, 0, 0>(A, DMODEL, B, DMODEL, C, DMODEL, nullptr,
                      T_TOK, z * 512, 512, blockIdx.y * 64, blockIdx.x * 128);
}

__global__ __launch_bounds__(256) void k_ffn1(const u16* __restrict__ Ag,
                                              const u16* __restrict__ Bg,
                                              u16* __restrict__ Cg,
                                              const float* __restrict__ biasg,
                                              const int* __restrict__ cntp,
                                              const int* __restrict__ offp) {
  int z = blockIdx.z;
  int Mloc = cntp[z];
  int m0 = blockIdx.y * 128;
  if (m0 >= Mloc) return;
  long o = offp[z];
  gemm_body<128, 1, 1>(Ag + o * DMODEL, DMODEL,
                       Bg + (long)z * FDIM * DMODEL, DMODEL,
                       (char*)(Cg + o * FDIM), FDIM,
                       biasg + (long)z * FDIM,
                       Mloc, 0, DMODEL, m0, blockIdx.x * 128);
}

__global__ __launch_bounds__(256) void k_ffn2(const u16* __restrict__ Ag,
                                              const u16* __restrict__ Bg,
                                              float* __restrict__ Cg,
                                              const float* __restrict__ biasg,
                                              const int* __restrict__ cntp,
                                              const int* __restrict__ offp) {
  int z = blockIdx.z;
  int Mloc = cntp[z];
  int m0 = blockIdx.y * 64;
  if (m0 >= Mloc) return;
  long o = offp[z];
  gemm_body<64, 0, 0>(Ag + o * FDIM, FDIM,
                      Bg + (long)z * DMODEL * FDIM, FDIM,
                      (char*)(Cg + o * DMODEL), DMODEL,
                      biasg + (long)z * DMODEL,
                      Mloc, 0, FDIM, m0, blockIdx.x * 128);
}

// ---------------------------------------------------------------------------
// V part of qkv -> Vt (B,H,HD,S) bf16 (transposed via LDS tile)
// ---------------------------------------------------------------------------
__global__ __launch_bounds__(256) void transpose_v(const u16* __restrict__ qkv,
                                                   u16* __restrict__ vt) {
  __shared__ u16 tile[64][65];
  int s0 = blockIdx.x * 64, bh = blockIdx.y;
  int b = bh >> 4, h = bh & 15;
  int r = threadIdx.x >> 3, c = (threadIdx.x & 7) * 8;
  for (int p = 0; p < 64; p += 32) {
    u16x8 v = *(const u16x8*)&qkv[(long)(b * SLEN + s0 + p + r) * 3072 + 2048 + h * 64 + c];
    for (int j = 0; j < 8; j++) tile[p + r][c + j] = v[j];
  }
  __syncthreads();
  for (int p = 0; p < 64; p += 32) {
    int d = p + r;
    u16x8 v;
    for (int j = 0; j < 8; j++) v[j] = tile[c + j][d];
    *(u16x8*)&vt[((long)bh * 64 + d) * SLEN + s0 + c] = v;
  }
}

// ---------------------------------------------------------------------------
// Fused flash attention: per (q-tile 128, b*h) block. Writes (B,S,D) bf16.
// ---------------------------------------------------------------------------
__global__ __launch_bounds__(256) void fused_attn(const u16* __restrict__ qkv,
                                                  const u16* __restrict__ vt,
                                                  u16* __restrict__ o2) {
  __shared__ u16 Qs[128][64];   // swizzled
  __shared__ u16 Ks[64][64];    // swizzled
  __shared__ u16 Vs[64][64];    // swizzled (rows = head-dim d, cols = 64 keys)
  __shared__ u16 Ps[128][72];   // padded

  int qt = blockIdx.x, bh = blockIdx.y;
  int b = bh >> 4, h = bh & 15;
  const u16* base = qkv + (long)b * SLEN * 3072 + h * 64;
  const u16* vbase = vt + (long)bh * HDIM * SLEN;

  int tid = threadIdx.x, lane = tid & 63, w = tid >> 6;
  int lrow = lane >> 3;
  int sg8 = ((lane & 7) ^ lrow) * 8;
  int q = lane >> 4, rr = lane & 15;
  int wm = w * 32;

  // stage Q once
  for (int p = 0; p < 4; p++) {
    int rb = p * 32 + w * 8;
    gl_lds16(base + (long)(qt * 128 + rb + lrow) * 3072 + sg8, &Qs[rb][0]);
  }

  f32x4 O[2][4];
  float mi[2][4], li[2][4];
  for (int i = 0; i < 2; i++)
    for (int r = 0; r < 4; r++) { mi[i][r] = -1e30f; li[i][r] = 0.f; }
  for (int i = 0; i < 2; i++)
    for (int jn = 0; jn < 4; jn++)
      for (int r = 0; r < 4; r++) O[i][jn][r] = 0.f;

  for (int kt = 0; kt < 16; kt++) {
    __syncthreads();
    for (int p = 0; p < 2; p++) {
      int rb = p * 32 + w * 8;
      gl_lds16(base + (long)(kt * 64 + rb + lrow) * 3072 + 1024 + sg8, &Ks[rb][0]);
      gl_lds16(vbase + (long)(rb + lrow) * SLEN + kt * 64 + sg8, &Vs[rb][0]);
    }
    __syncthreads();

    // S = Q @ K^T
    f32x4 S[2][4];
    for (int i = 0; i < 2; i++)
      for (int j = 0; j < 4; j++)
        for (int r = 0; r < 4; r++) S[i][j][r] = 0.f;
    for (int ks = 0; ks < 2; ks++) {
      int slot = (((ks * 4 + q) ^ (rr & 7)) * 8);
      s16x8 aq0 = *(const s16x8*)&Qs[wm + rr][slot];
      s16x8 aq1 = *(const s16x8*)&Qs[wm + 16 + rr][slot];
      for (int j = 0; j < 4; j++) {
        s16x8 bk = *(const s16x8*)&Ks[j * 16 + rr][slot];
        S[0][j] = __builtin_amdgcn_mfma_f32_16x16x32_bf16(aq0, bk, S[0][j], 0, 0, 0);
        S[1][j] = __builtin_amdgcn_mfma_f32_16x16x32_bf16(aq1, bk, S[1][j], 0, 0, 0);
      }
    }

    // online softmax
    for (int i = 0; i < 2; i++) {
      for (int r = 0; r < 4; r++) {
        float mx = -1e30f;
        for (int j = 0; j < 4; j++) mx = fmaxf(mx, S[i][j][r]);
        for (int o = 1; o < 16; o <<= 1) mx = fmaxf(mx, __shfl_xor(mx, o));
        mx *= 0.125f;
        float mnew = fmaxf(mi[i][r], mx);
        float al = __expf(mi[i][r] - mnew);
        mi[i][r] = mnew;
        float ps = 0.f;
        for (int j = 0; j < 4; j++) {
          float e = __expf(S[i][j][r] * 0.125f - mnew);
          S[i][j][r] = e;
          ps += e;
        }
        for (int o = 1; o < 16; o <<= 1) ps += __shfl_xor(ps, o);
        li[i][r] = li[i][r] * al + ps;
        for (int jn = 0; jn < 4; jn++) O[i][jn][r] *= al;
      }
    }

    // P -> LDS (C-layout scatter)
    for (int i = 0; i < 2; i++)
      for (int j = 0; j < 4; j++)
        for (int r = 0; r < 4; r++)
          Ps[wm + i * 16 + q * 4 + r][j * 16 + rr] = f2bf(S[i][j][r]);
    __syncthreads();

    // O += P @ V
    for (int ks = 0; ks < 2; ks++) {
      s16x8 ap0 = *(const s16x8*)&Ps[wm + rr][ks * 32 + q * 8];
      s16x8 ap1 = *(const s16x8*)&Ps[wm + 16 + rr][ks * 32 + q * 8];
      int slot = (((ks * 4 + q) ^ (rr & 7)) * 8);
      for (int jn = 0; jn < 4; jn++) {
        s16x8 bv = *(const s16x8*)&Vs[jn * 16 + rr][slot];
        O[0][jn] = __builtin_amdgcn_mfma_f32_16x16x32_bf16(ap0, bv, O[0][jn], 0, 0, 0);
        O[1][jn] = __builtin_amdgcn_mfma_f32_16x16x32_bf16(ap1, bv, O[1][jn], 0, 0, 0);
      }
    }
  }

  for (int i = 0; i < 2; i++)
    for (int r = 0; r < 4; r++) {
      float inv = 1.f / li[i][r];
      int s = qt * 128 + wm + i * 16 + q * 4 + r;
      long rowp = ((long)(b * SLEN + s)) * DMODEL + h * 64;
      for (int jn = 0; jn < 4; jn++)
        o2[rowp + jn * 16 + rr] = f2bf(O[i][jn][r] * inv);
    }
}

// ---------------------------------------------------------------------------
// residual add (+out-proj bias, 2 split-K partials) + LayerNorm -> fp32+bf16
// ---------------------------------------------------------------------------
__global__ __launch_bounds__(256) void add_ln(const float* __restrict__ a,
                                              const float* __restrict__ p0,
                                              const float* __restrict__ p1,
                                              const float* __restrict__ ob,
                                              const float* __restrict__ g,
                                              const float* __restrict__ bb,
                                              float* __restrict__ xf, u16* __restrict__ xb) {
  int t = blockIdx.x, tid = threadIdx.x;
  float4 va = ((const float4*)(a + (long)t * DMODEL))[tid];
  float4 v0v = ((const float4*)(p0 + (long)t * DMODEL))[tid];
  float4 v1v = ((const float4*)(p1 + (long)t * DMODEL))[tid];
  float4 vo = ((const float4*)ob)[tid];
  float v0 = va.x + v0v.x + v1v.x + vo.x;
  float v1 = va.y + v0v.y + v1v.y + vo.y;
  float v2 = va.z + v0v.z + v1v.z + vo.z;
  float v3 = va.w + v0v.w + v1v.w + vo.w;
  float s = v0 + v1 + v2 + v3;
  float s2 = v0 * v0 + v1 * v1 + v2 * v2 + v3 * v3;
  __shared__ float sa[4], sb[4];
  for (int o = 32; o; o >>= 1) { s += __shfl_down(s, o); s2 += __shfl_down(s2, o); }
  int lane = tid & 63, w = tid >> 6;
  if (lane == 0) { sa[w] = s; sb[w] = s2; }
  __syncthreads();
  s = sa[0] + sa[1] + sa[2] + sa[3];
  s2 = sb[0] + sb[1] + sb[2] + sb[3];
  float mu = s * (1.f / DMODEL);
  float var = s2 * (1.f / DMODEL) - mu * mu;
  float rs = rsqrtf(var + LN_EPS);
  float4 gg = ((const float4*)g)[tid];
  float4 bv = ((const float4*)bb)[tid];
  float4 o;
  o.x = (v0 - mu) * rs * gg.x + bv.x;
  o.y = (v1 - mu) * rs * gg.y + bv.y;
  o.z = (v2 - mu) * rs * gg.z + bv.z;
  o.w = (v3 - mu) * rs * gg.w + bv.w;
  ((float4*)(xf + (long)t * DMODEL))[tid] = o;
  u16x4 obv;
  obv[0] = f2bf(o.x); obv[1] = f2bf(o.y); obv[2] = f2bf(o.z); obv[3] = f2bf(o.w);
  ((u16x4*)(xb + (long)t * DMODEL))[tid] = obv;
}

// ---------------------------------------------------------------------------
// Gate: logits, full softmax (usage/aux), top-2 routing lists
// ---------------------------------------------------------------------------
__global__ __launch_bounds__(256) void gate_kernel(
    const float* __restrict__ xf, const float* __restrict__ gw, const float* __restrict__ gb,
    int* __restrict__ cnt, int* __restrict__ tok_list,
    int* __restrict__ tk_e, int* __restrict__ tk_pos, float* __restrict__ tk_prob,
    float* __restrict__ usage) {
  int wid = threadIdx.x >> 6, lane = threadIdx.x & 63;
  int t = blockIdx.x * 4 + wid;
  float xv[16];
  for (int j = 0; j < 16; j++) xv[j] = xf[(long)t * DMODEL + j * 64 + lane];
  float l[8];
  for (int e = 0; e < 8; e++) {
    float d = 0.f;
    for (int j = 0; j < 16; j++) d += xv[j] * gw[e * DMODEL + j * 64 + lane];
    for (int o = 32; o; o >>= 1) d += __shfl_down(d, o);
    l[e] = d;  // valid on lane 0 only
  }
  __shared__ float us[8];
  if (threadIdx.x < 8) us[threadIdx.x] = 0.f;
  __syncthreads();
  if (lane == 0) {
    float mx = -1e30f;
    for (int e = 0; e < 8; e++) { l[e] += gb[e]; mx = fmaxf(mx, l[e]); }
    float ex[8], sum = 0.f;
    for (int e = 0; e < 8; e++) { ex[e] = expf(l[e] - mx); sum += ex[e]; }
    float inv = 1.f / sum;
    for (int e = 0; e < 8; e++) atomicAdd(&us[e], ex[e] * inv);
    int i1 = 0;
    for (int e = 1; e < 8; e++) if (l[e] > l[i1]) i1 = e;
    int i2 = (i1 == 0) ? 1 : 0;
    for (int e = 0; e < 8; e++) if (e != i1 && l[e] > l[i2]) i2 = e;
    float bb = expf(l[i2] - l[i1]);
    float p1 = 1.f / (1.f + bb), p2 = bb / (1.f + bb);
    int pos1 = atomicAdd(&cnt[i1], 1);
    tok_list[i1 * 2048 + pos1] = t;
    tk_e[2 * t] = i1; tk_pos[2 * t] = pos1; tk_prob[2 * t] = p1;
    int pos2 = atomicAdd(&cnt[i2], 1);
    tok_list[i2 * 2048 + pos2] = t;
    tk_e[2 * t + 1] = i2; tk_pos[2 * t + 1] = pos2; tk_prob[2 * t + 1] = p2;
  }
  __syncthreads();
  if (threadIdx.x < 8) atomicAdd(&usage[threadIdx.x], us[threadIdx.x]);
}

__global__ void finalize_gate(const int* __restrict__ cnt, int* __restrict__ offp,
                              const float* __restrict__ usage, float* __restrict__ aux_out) {
  if (threadIdx.x == 0) {
    int o = 0;
    for (int e = 0; e < 8; e++) { offp[e] = o; o += cnt[e]; }
    float s = 0.f;
    for (int e = 0; e < 8; e++) { float u = usage[e] * (1.f / T_TOK); s += u * u; }
    aux_out[0] = (float)NEXP * s;
  }
}

// gather x rows per expert into compact buffer
__global__ __launch_bounds__(256) void gather_x(const u16* __restrict__ xb,
                                                const int* __restrict__ cnt,
                                                const int* __restrict__ offp,
                                                const int* __restrict__ tok_list,
                                                u16* __restrict__ xg) {
  int e = blockIdx.y, i = blockIdx.x;
  if (i >= cnt[e]) return;
  int t = tok_list[e * 2048 + i];
  long j = offp[e] + i;
  ((uint2*)(xg + j * DMODEL))[threadIdx.x] =
      ((const uint2*)(xb + (long)t * DMODEL))[threadIdx.x];
}

// weighted expert-output combine + residual + LN2 -> final output
__global__ __launch_bounds__(256) void moe_ln2(
    const float* __restrict__ xf, const float* __restrict__ y,
    const int* __restrict__ offp, const int* __restrict__ tk_e,
    const int* __restrict__ tk_pos, const float* __restrict__ tk_prob,
    const float* __restrict__ g, const float* __restrict__ bb, float* __restrict__ out) {
  int t = blockIdx.x, tid = threadIdx.x;
  int e0 = tk_e[2 * t], e1 = tk_e[2 * t + 1];
  long j0 = (long)offp[e0] + tk_pos[2 * t];
  long j1 = (long)offp[e1] + tk_pos[2 * t + 1];
  float p0 = tk_prob[2 * t], p1 = tk_prob[2 * t + 1];
  float4 vx = ((const float4*)(xf + (long)t * DMODEL))[tid];
  float4 y0 = ((const float4*)(y + j0 * DMODEL))[tid];
  float4 y1 = ((const float4*)(y + j1 * DMODEL))[tid];
  float v0 = vx.x + p0 * y0.x + p1 * y1.x;
  float v1 = vx.y + p0 * y0.y + p1 * y1.y;
  float v2 = vx.z + p0 * y0.z + p1 * y1.z;
  float v3 = vx.w + p0 * y0.w + p1 * y1.w;
  float s = v0 + v1 + v2 + v3;
  float s2 = v0 * v0 + v1 * v1 + v2 * v2 + v3 * v3;
  __shared__ float sa[4], sb[4];
  for (int o = 32; o; o >>= 1) { s += __shfl_down(s, o); s2 += __shfl_down(s2, o); }
  int lane = tid & 63, w = tid >> 6;
  if (lane == 0) { sa[w] = s; sb[w] = s2; }
  __syncthreads();
  s = sa[0] + sa[1] + sa[2] + sa[3];
  s2 = sb[0] + sb[1] + sb[2] + sb[3];
  float mu = s * (1.f / DMODEL);
  float var = s2 * (1.f / DMODEL) - mu * mu;
  float rs = rsqrtf(var + LN_EPS);
  float4 gg = ((const float4*)g)[tid];
  float4 bv = ((const float4*)bb)[tid];
  float4 o;
  o.x = (v0 - mu) * rs * gg.x + bv.x;
  o.y = (v1 - mu) * rs * gg.y + bv.y;
  o.z = (v2 - mu) * rs * gg.z + bv.z;
  o.w = (v3 - mu) * rs * gg.w + bv.w;
  ((float4*)(out + (long)t * DMODEL))[tid] = o;
}

// ---------------------------------------------------------------------------
extern "C" void kernel_launch(void* const* d_in, const int* in_sizes, int n_in,
                              void* d_out, int out_size, void* d_ws, size_t ws_size,
                              hipStream_t stream) {
  const float* src  = (const float*)d_in[0];
  const float* inw  = (const float*)d_in[1];
  const float* inb  = (const float*)d_in[2];
  const float* outw = (const float*)d_in[3];
  const float* outb = (const float*)d_in[4];
  const float* gw   = (const float*)d_in[5];
  const float* gb   = (const float*)d_in[6];
  const float* w1   = (const float*)d_in[7];
  const float* b1   = (const float*)d_in[8];
  const float* w2   = (const float*)d_in[9];
  const float* b2   = (const float*)d_in[10];
  const float* g1   = (const float*)d_in[11];
  const float* bb1  = (const float*)d_in[12];
  const float* g2   = (const float*)d_in[13];
  const float* bb2  = (const float*)d_in[14];
  float* out = (float*)d_out;

  char* w = (char*)d_ws;
  auto alloc = [&](size_t bytes) {
    char* p = w;
    w += (bytes + 255) & ~(size_t)255;
    return p;
  };

  int*   cnt     = (int*)alloc(8 * 4);
  int*   offp    = (int*)alloc(8 * 4);
  float* usage   = (float*)alloc(8 * 4);
  int*   tok_list= (int*)alloc((size_t)NEXP * 2048 * 4);
  int*   tk_e    = (int*)alloc((size_t)2 * T_TOK * 4);
  int*   tk_pos  = (int*)alloc((size_t)2 * T_TOK * 4);
  float* tk_prob = (float*)alloc((size_t)2 * T_TOK * 4);

  u16* src_bf  = (u16*)alloc((size_t)T_TOK * DMODEL * 2);
  u16* inw_bf  = (u16*)alloc((size_t)3 * DMODEL * DMODEL * 2);
  u16* outw_bf = (u16*)alloc((size_t)DMODEL * DMODEL * 2);
  u16* w1_bf   = (u16*)alloc((size_t)NEXP * FDIM * DMODEL * 2);
  u16* w2_bf   = (u16*)alloc((size_t)NEXP * DMODEL * FDIM * 2);
  u16* qkv_bf  = (u16*)alloc((size_t)T_TOK * 3 * DMODEL * 2);
  u16* vt_bf   = (u16*)alloc((size_t)T_TOK * DMODEL * 2);    // (B,H,HD,S)
  u16* o2_bf   = (u16*)alloc((size_t)T_TOK * DMODEL * 2);    // (B,S,D)
  float* attn_p= (float*)alloc((size_t)2 * T_TOK * DMODEL * 4);  // 2 split-K partials
  float* x_f   = (float*)alloc((size_t)T_TOK * DMODEL * 4);
  u16* x_bf    = (u16*)alloc((size_t)T_TOK * DMODEL * 2);
  u16* xg_bf   = (u16*)alloc((size_t)2 * T_TOK * DMODEL * 2);
  u16* h_bf    = (u16*)alloc((size_t)2 * T_TOK * FDIM * 2);
  float* y_f   = (float*)alloc((size_t)2 * T_TOK * DMODEL * 4);
  (void)ws_size; (void)n_in; (void)in_sizes; (void)out_size;

  hipMemsetAsync(cnt, 0, 3 * 256, stream);  // cnt, offp, usage regions

  // bf16 conversions
  cvt_small<<<(T_TOK * DMODEL / 4 + 255) / 256, 256, 0, stream>>>(src, src_bf, T_TOK * DMODEL / 4);
  cvt_small<<<(3 * DMODEL * DMODEL / 4 + 255) / 256, 256, 0, stream>>>(inw, inw_bf, 3L * DMODEL * DMODEL / 4);
  cvt_small<<<(DMODEL * DMODEL / 4 + 255) / 256, 256, 0, stream>>>(outw, outw_bf, (long)DMODEL * DMODEL / 4);
  cvt_w1<<<(int)((long)NEXP * FDIM * DMODEL / 4 / 256), 256, 0, stream>>>(w1, w1_bf, (long)NEXP * FDIM * DMODEL / 4);
  cvt_w2<<<(int)((long)NEXP * DMODEL * FDIM / 4 / 256), 256, 0, stream>>>(w2, w2_bf, (long)NEXP * DMODEL * FDIM / 4);

  // QKV projection: (2048x1024) @ (3072x1024)^T + b -> bf16
  k_qkv<<<dim3(24, 32), 256, 0, stream>>>(src_bf, inw_bf, qkv_bf, inb);

  transpose_v<<<dim3(16, 32), 256, 0, stream>>>(qkv_bf, vt_bf);

  // fused flash attention -> o2_bf (B,S,D)
  fused_attn<<<dim3(8, 32), 256, 0, stream>>>(qkv_bf, vt_bf, o2_bf);

  // output projection, split-K=2 -> two fp32 partials (bias folded into add_ln)
  k_outp<<<dim3(8, 32, 2), 256, 0, stream>>>(o2_bf, outw_bf, attn_p);

  // residual + out-proj bias + LN1
  add_ln<<<T_TOK, 256, 0, stream>>>(src, attn_p, attn_p + (long)T_TOK * DMODEL,
                                    outb, g1, bb1, x_f, x_bf);

  // gate + routing
  gate_kernel<<<T_TOK / 4, 256, 0, stream>>>(x_f, gw, gb, cnt, tok_list,
                                             tk_e, tk_pos, tk_prob, usage);
  finalize_gate<<<1, 64, 0, stream>>>(cnt, offp, usage, out + (long)T_TOK * DMODEL);

  gather_x<<<dim3(2048, 8), 256, 0, stream>>>(x_bf, cnt, offp, tok_list, xg_bf);

  // FFN1 (grouped, gelu fused) -> bf16
  k_ffn1<<<dim3(32, 16, 8), 256, 0, stream>>>(xg_bf, w1_bf, h_bf, b1, cnt, offp);

  // FFN2 (grouped) -> fp32
  k_ffn2<<<dim3(8, 32, 8), 256, 0, stream>>>(h_bf, w2_bf, y_f, b2, cnt, offp);

  // combine + residual + LN2 -> output
  moe_ln2<<<T_TOK, 256, 0, stream>>>(x_f, y_f, offp, tk_e, tk_pos, tk_prob,
                                     g2, bb2, out);
}